// Round 14
// baseline (224.867 us; speedup 1.0000x reference)
//
#include <hip/hip_runtime.h>

#define L_SEQ 4096
#define DM 128
#define DIN 256
#define NC 128       // scan chunks
#define CHUNK 32     // L_SEQ / NC

// ---------------- K1: ConvTranspose2d(2x2,s2) + bias + concat -> seq (B,L,128)
__global__ __launch_bounds__(256) void upcat_kernel(
    const float* __restrict__ x, const float* __restrict__ skip,
    const float* __restrict__ up_w, const float* __restrict__ up_b,
    float* __restrict__ seq) {
  int b = blockIdx.x >> 6, hh = blockIdx.x & 63;
  int h = hh >> 1, i = hh & 1;
  int tid = threadIdx.x;
  __shared__ float xs[128][32];      // x[b][c][h][:]
  __shared__ float wsh[2][128][64];  // [j][c][o] for this i
  for (int e = tid; e < 1024; e += 256) {
    int c = e >> 3, q = e & 7;
    *(float4*)&xs[c][q * 4] =
        *(const float4*)(x + (((size_t)b * 128 + c) * 32 + h) * 32 + q * 4);
  }
  for (int e = tid; e < 8192; e += 256) {
    int c = e >> 6, o = e & 63;
    float2 v = *(const float2*)(up_w + c * 256 + o * 4 + i * 2);
    wsh[0][c][o] = v.x;
    wsh[1][c][o] = v.y;
  }
  __syncthreads();
  int tx = tid & 15, ty = tid >> 4;  // o-quad, ww-quad
  float4 bv = *(const float4*)(up_b + tx * 4);
  float acc[4][4];                   // [a -> ww=ty*4+a][o]
#pragma unroll
  for (int a = 0; a < 4; ++a) {
    acc[a][0] = bv.x; acc[a][1] = bv.y; acc[a][2] = bv.z; acc[a][3] = bv.w;
  }
#pragma unroll 4
  for (int c = 0; c < 128; ++c) {
    float x0 = xs[c][ty * 2];        // ww = 4ty+0,1  (w = 2ty)
    float x1 = xs[c][ty * 2 + 1];    // ww = 4ty+2,3  (w = 2ty+1)
    float4 w0 = *(const float4*)&wsh[0][c][tx * 4];
    float4 w1 = *(const float4*)&wsh[1][c][tx * 4];
    acc[0][0] = fmaf(x0, w0.x, acc[0][0]); acc[0][1] = fmaf(x0, w0.y, acc[0][1]);
    acc[0][2] = fmaf(x0, w0.z, acc[0][2]); acc[0][3] = fmaf(x0, w0.w, acc[0][3]);
    acc[1][0] = fmaf(x0, w1.x, acc[1][0]); acc[1][1] = fmaf(x0, w1.y, acc[1][1]);
    acc[1][2] = fmaf(x0, w1.z, acc[1][2]); acc[1][3] = fmaf(x0, w1.w, acc[1][3]);
    acc[2][0] = fmaf(x1, w0.x, acc[2][0]); acc[2][1] = fmaf(x1, w0.y, acc[2][1]);
    acc[2][2] = fmaf(x1, w0.z, acc[2][2]); acc[2][3] = fmaf(x1, w0.w, acc[2][3]);
    acc[3][0] = fmaf(x1, w1.x, acc[3][0]); acc[3][1] = fmaf(x1, w1.y, acc[3][1]);
    acc[3][2] = fmaf(x1, w1.z, acc[3][2]); acc[3][3] = fmaf(x1, w1.w, acc[3][3]);
  }
  size_t mrow_base = (size_t)b * L_SEQ + (size_t)hh * 64;
#pragma unroll
  for (int a = 0; a < 4; ++a) {
    int ww = ty * 4 + a;
    *(float4*)(seq + (mrow_base + ww) * DM + tx * 4) =
        make_float4(acc[a][0], acc[a][1], acc[a][2], acc[a][3]);
  }
  // skip half: channels 64..127
  for (int e = tid; e < 4096; e += 256) {
    int c = e & 63, ww = e >> 6;
    seq[(mrow_base + ww) * DM + 64 + c] =
        skip[((size_t)b * 64 + c) * (size_t)L_SEQ + hh * 64 + ww];
  }
}

// ---------------- K2: in_proj GEMM, wave-uniform s_load weights.
// grid (M/64, 4); block 512 (8 waves). lane = row, wave owns 16 of the
// block's 128 output cols -> W reads are scalar loads; LDS traffic is one
// ds_read_b32 per k per thread (8 FLOP/B, VALU-bound).
__global__ __launch_bounds__(512) void inproj_kernel(
    const float* __restrict__ seq, const float* __restrict__ W,
    float* __restrict__ xz) {
  __shared__ float us[64][133];   // seq tile, pad 133 (5*lane mod 32 -> no conflict)
  __shared__ float ot[64][129];   // result tile for coalesced store
  int m0 = blockIdx.x * 64;
  int cb0 = blockIdx.y * 128;
  int tid = threadIdx.x;
  int lane = tid & 63;
  int w = __builtin_amdgcn_readfirstlane(tid >> 6);  // 0..7
  const float* Wrow = W + (size_t)(cb0 + w * 16) * 128;
#pragma unroll
  for (int i = 0; i < 4; ++i) {
    int e = tid + i * 512;
    int r = e >> 5, cq = e & 31;
    *(float4*)&us[r][cq * 4] =
        *(const float4*)(seq + (size_t)(m0 + r) * 128 + cq * 4);
  }
  __syncthreads();
  float acc[16];
#pragma unroll
  for (int j = 0; j < 16; ++j) acc[j] = 0.f;
#pragma unroll 4
  for (int k = 0; k < 128; ++k) {
    float v = us[lane][k];
#pragma unroll
    for (int j = 0; j < 16; ++j)
      acc[j] = fmaf(v, Wrow[j * 128 + k], acc[j]);
  }
#pragma unroll
  for (int q = 0; q < 4; ++q)
    *(float4*)&ot[lane][w * 16 + q * 4] =
        make_float4(acc[q * 4], acc[q * 4 + 1], acc[q * 4 + 2], acc[q * 4 + 3]);
  __syncthreads();
#pragma unroll
  for (int i = 0; i < 4; ++i) {
    int e = tid + i * 512;
    int r = e >> 5, cq = e & 31;
    *(float4*)(xz + (size_t)(m0 + r) * 512 + cb0 + cq * 4) =
        *(const float4*)&ot[r][cq * 4];
  }
}

// ---------------- K4: fused conv1d+silu+xproj: xz -> u (global), dbc
__global__ __launch_bounds__(256) void xproj_kernel(
    const float* __restrict__ xz, const float* __restrict__ cw,
    const float* __restrict__ cb, const float* __restrict__ W,
    float* __restrict__ dbc, float* __restrict__ u_out) {
  __shared__ float xzt[67][64];  // raw xz rows (m0-3+rr)
  __shared__ float us[64][68];   // silu(conv(xz)) = u tile, pad 68
  int m0 = blockIdx.x * 64;
  int tid = threadIdx.x;
  int lane = tid & 63;
  int w = __builtin_amdgcn_readfirstlane(tid >> 6);  // wave-uniform 0..3
  int jbase = blockIdx.y * 20 + w * 5;
  const float* Wb = W + jbase * 256;
  bool first = (m0 & (L_SEQ - 1)) == 0;  // block at sequence start
  int cc4 = (tid & 15) << 2;             // conv-phase column group
  int r0 = tid >> 4;                     // conv-phase row base
  float acc[5];
#pragma unroll
  for (int j = 0; j < 5; ++j) acc[j] = 0.f;
  for (int k0 = 0; k0 < 256; k0 += 64) {
    __syncthreads();
    for (int e = tid; e < 67 * 16; e += 256) {
      int rr = e >> 4, c4 = (e & 15) << 2;
      float4 v;
      if (first && rr < 3)
        v = make_float4(0.f, 0.f, 0.f, 0.f);
      else
        v = *(const float4*)(xz + (size_t)(m0 - 3 + rr) * 512 + k0 + c4);
      *(float4*)&xzt[rr][c4] = v;
    }
    __syncthreads();
    {
      int d = k0 + cc4;
      float4 cw0 = *(const float4*)(cw + (d + 0) * 4);
      float4 cw1 = *(const float4*)(cw + (d + 1) * 4);
      float4 cw2 = *(const float4*)(cw + (d + 2) * 4);
      float4 cw3 = *(const float4*)(cw + (d + 3) * 4);
      float4 cbv = *(const float4*)(cb + d);
#pragma unroll
      for (int s = 0; s < 4; ++s) {
        int r = r0 + s * 16;
        float a0 = cbv.x, a1 = cbv.y, a2 = cbv.z, a3 = cbv.w;
        a0 = fmaf(xzt[r + 0][cc4 + 0], cw0.x, a0);
        a0 = fmaf(xzt[r + 1][cc4 + 0], cw0.y, a0);
        a0 = fmaf(xzt[r + 2][cc4 + 0], cw0.z, a0);
        a0 = fmaf(xzt[r + 3][cc4 + 0], cw0.w, a0);
        a1 = fmaf(xzt[r + 0][cc4 + 1], cw1.x, a1);
        a1 = fmaf(xzt[r + 1][cc4 + 1], cw1.y, a1);
        a1 = fmaf(xzt[r + 2][cc4 + 1], cw1.z, a1);
        a1 = fmaf(xzt[r + 3][cc4 + 1], cw1.w, a1);
        a2 = fmaf(xzt[r + 0][cc4 + 2], cw2.x, a2);
        a2 = fmaf(xzt[r + 1][cc4 + 2], cw2.y, a2);
        a2 = fmaf(xzt[r + 2][cc4 + 2], cw2.z, a2);
        a2 = fmaf(xzt[r + 3][cc4 + 2], cw2.w, a2);
        a3 = fmaf(xzt[r + 0][cc4 + 3], cw3.x, a3);
        a3 = fmaf(xzt[r + 1][cc4 + 3], cw3.y, a3);
        a3 = fmaf(xzt[r + 2][cc4 + 3], cw3.z, a3);
        a3 = fmaf(xzt[r + 3][cc4 + 3], cw3.w, a3);
        float o0 = a0 / (1.f + __expf(-a0));
        float o1 = a1 / (1.f + __expf(-a1));
        float o2 = a2 / (1.f + __expf(-a2));
        float o3 = a3 / (1.f + __expf(-a3));
        *(float4*)&us[r][cc4] = make_float4(o0, o1, o2, o3);
        if (blockIdx.y == 0)
          *(float4*)(u_out + (size_t)(m0 + r) * 256 + d) =
              make_float4(o0, o1, o2, o3);
      }
    }
    __syncthreads();
#pragma unroll
    for (int kk = 0; kk < 64; kk += 4) {
      float4 a4 = *(const float4*)&us[lane][kk];
      float a_[4] = {a4.x, a4.y, a4.z, a4.w};
#pragma unroll
      for (int i = 0; i < 4; ++i)
#pragma unroll
        for (int j = 0; j < 5; ++j)
          acc[j] = fmaf(a_[i], Wb[j * 256 + k0 + kk + i], acc[j]);
    }
  }
  size_t base = (size_t)(m0 + lane) * 40 + jbase;
#pragma unroll
  for (int j = 0; j < 5; ++j) dbc[base + j] = acc[j];
}

// ---------------- K5: chunked parallel selective scan ----------------
__device__ __forceinline__ float softplus_f(float a) {
  return (a > 20.f) ? a : log1pf(__expf(a));
}

__global__ __launch_bounds__(256) void scan_pass1(
    const float* __restrict__ u, const float* __restrict__ dbc,
    const float* __restrict__ A_log, const float* __restrict__ Wdt,
    const float* __restrict__ bdt, float* __restrict__ carryA,
    float* __restrict__ carryH) {
  int bid = blockIdx.x;          // b*NC + c
  int b = bid >> 7;
  int c = bid & (NC - 1);
  int d = threadIdx.x;
  __shared__ float ls[CHUNK * 40];
  size_t l0 = (size_t)b * L_SEQ + (size_t)c * CHUNK;
  const float* rp = dbc + l0 * 40;
  for (int e = d; e < CHUNK * 40; e += 256) ls[e] = rp[e];
  float Ac[16];
  {
    const float4* ar = (const float4*)(A_log + d * 16);
#pragma unroll
    for (int q = 0; q < 4; ++q) {
      float4 v = ar[q];
      Ac[q * 4 + 0] = -__expf(v.x); Ac[q * 4 + 1] = -__expf(v.y);
      Ac[q * 4 + 2] = -__expf(v.z); Ac[q * 4 + 3] = -__expf(v.w);
    }
  }
  float wdt[8];
  {
    const float4* wr = (const float4*)(Wdt + d * 8);
    float4 v0 = wr[0], v1 = wr[1];
    wdt[0] = v0.x; wdt[1] = v0.y; wdt[2] = v0.z; wdt[3] = v0.w;
    wdt[4] = v1.x; wdt[5] = v1.y; wdt[6] = v1.z; wdt[7] = v1.w;
  }
  float bdt_v = bdt[d];
  const float* up = u + l0 * 256 + d;
  __syncthreads();
  float h[16];
#pragma unroll
  for (int n = 0; n < 16; ++n) h[n] = 0.f;
  float dvs = 0.f;
#pragma unroll 4
  for (int li = 0; li < CHUNK; ++li) {
    float uv = up[(size_t)li * 256];
    float acc = bdt_v;
#pragma unroll
    for (int j = 0; j < 8; ++j)
      acc = fmaf(ls[li * 40 + j], wdt[j], acc);
    float dv = softplus_f(acc);
    dvs += dv;
    float t = dv * uv;
#pragma unroll
    for (int n = 0; n < 16; ++n) {
      float dA = __expf(dv * Ac[n]);
      h[n] = fmaf(dA, h[n], t * ls[li * 40 + 8 + n]);
    }
  }
  float4* cA = (float4*)(carryA + ((size_t)bid * 256 + d) * 16);
  float4* cH = (float4*)(carryH + ((size_t)bid * 256 + d) * 16);
#pragma unroll
  for (int q = 0; q < 4; ++q) {
    // prod of dA over chunk == exp(sum(dv) * Ac)
    cA[q] = make_float4(__expf(dvs * Ac[q * 4]), __expf(dvs * Ac[q * 4 + 1]),
                        __expf(dvs * Ac[q * 4 + 2]), __expf(dvs * Ac[q * 4 + 3]));
    cH[q] = make_float4(h[q * 4], h[q * 4 + 1], h[q * 4 + 2], h[q * 4 + 3]);
  }
}

__global__ __launch_bounds__(64) void scan_mid(
    const float* __restrict__ carryA, float* __restrict__ carryH) {
  int gid = blockIdx.x * 64 + threadIdx.x;  // 16384 chains
  int b = gid >> 12;
  int dn = gid & 4095;
  size_t i = ((size_t)(b * NC) << 12) + dn;
  float h = 0.f;
  float a = carryA[i], hl = carryH[i];
#pragma unroll 4
  for (int c = 0; c < NC - 1; ++c) {
    size_t i2 = i + 4096;
    float a2 = carryA[i2];
    float hl2 = carryH[i2];
    carryH[i] = h;                 // h entering chunk c
    h = fmaf(a, h, hl);
    a = a2; hl = hl2; i = i2;
  }
  carryH[i] = h;                   // h entering last chunk
}

__global__ __launch_bounds__(256) void scan_pass3(
    const float* __restrict__ u, const float* __restrict__ dbc,
    const float* __restrict__ xz, const float* __restrict__ A_log,
    const float* __restrict__ Wdt, const float* __restrict__ bdt,
    const float* __restrict__ Dp, const float* __restrict__ carryH,
    float* __restrict__ y) {
  int bid = blockIdx.x;
  int b = bid >> 7;
  int c = bid & (NC - 1);
  int d = threadIdx.x;
  __shared__ float ls[CHUNK * 40];
  size_t l0 = (size_t)b * L_SEQ + (size_t)c * CHUNK;
  const float* rp = dbc + l0 * 40;
  for (int e = d; e < CHUNK * 40; e += 256) ls[e] = rp[e];
  float Ac[16];
  {
    const float4* ar = (const float4*)(A_log + d * 16);
#pragma unroll
    for (int q = 0; q < 4; ++q) {
      float4 v = ar[q];
      Ac[q * 4 + 0] = -__expf(v.x); Ac[q * 4 + 1] = -__expf(v.y);
      Ac[q * 4 + 2] = -__expf(v.z); Ac[q * 4 + 3] = -__expf(v.w);
    }
  }
  float wdt[8];
  {
    const float4* wr = (const float4*)(Wdt + d * 8);
    float4 v0 = wr[0], v1 = wr[1];
    wdt[0] = v0.x; wdt[1] = v0.y; wdt[2] = v0.z; wdt[3] = v0.w;
    wdt[4] = v1.x; wdt[5] = v1.y; wdt[6] = v1.z; wdt[7] = v1.w;
  }
  float bdt_v = bdt[d];
  float Dv = Dp[d];
  float h[16];
  {
    const float4* cH = (const float4*)(carryH + ((size_t)bid * 256 + d) * 16);
#pragma unroll
    for (int q = 0; q < 4; ++q) {
      float4 v = cH[q];
      h[q * 4 + 0] = v.x; h[q * 4 + 1] = v.y;
      h[q * 4 + 2] = v.z; h[q * 4 + 3] = v.w;
    }
  }
  const float* up = u + l0 * 256 + d;
  const float* zp = xz + l0 * 512 + 256 + d;
  float* yp = y + l0 * 256 + d;
  __syncthreads();
#pragma unroll 4
  for (int li = 0; li < CHUNK; ++li) {
    float uv = up[(size_t)li * 256];
    float zv = zp[(size_t)li * 512];
    float acc = bdt_v;
#pragma unroll
    for (int j = 0; j < 8; ++j)
      acc = fmaf(ls[li * 40 + j], wdt[j], acc);
    float dv = softplus_f(acc);
    float t = dv * uv;
    float p = 0.f;
#pragma unroll
    for (int n = 0; n < 16; ++n) {
      float dA = __expf(dv * Ac[n]);
      h[n] = fmaf(dA, h[n], t * ls[li * 40 + 8 + n]);
      p = fmaf(h[n], ls[li * 40 + 24 + n], p);
    }
    float s = zv / (1.f + __expf(-zv));
    yp[(size_t)li * 256] = (p + uv * Dv) * s;
  }
}

// ---------------- K6: fused out_proj GEMM + LayerNorm + silu + 1x1 conv
// 512 threads. GEMM phase: lane = row, wave owns 16 of 128 channels ->
// Wp reads via s_load (scalar pipe); LDS = 1 ds_read_b32 per k (8 FLOP/B).
__global__ __launch_bounds__(512) void fused_out_kernel(
    const float* __restrict__ y, const float* __restrict__ Wp,
    const float* __restrict__ gamma, const float* __restrict__ beta,
    const float* __restrict__ Wo, const float* __restrict__ bo,
    float* __restrict__ out) {
  __shared__ float us[64][133];   // y-tile k-chunk, pad 133 -> conflict-free
  __shared__ float xt[64][129];
  __shared__ float mus[64], invs[64];
  int tid = threadIdx.x;
  int m0 = blockIdx.x * 64;
  int lane = tid & 63;
  int w = __builtin_amdgcn_readfirstlane(tid >> 6);  // 0..7
  float acc[16];
#pragma unroll
  for (int j = 0; j < 16; ++j) acc[j] = 0.f;
  for (int kc = 0; kc < 256; kc += 128) {
    __syncthreads();
#pragma unroll
    for (int i = 0; i < 4; ++i) {
      int e = tid + i * 512;
      int r = e >> 5, cq = e & 31;
      *(float4*)&us[r][cq * 4] =
          *(const float4*)(y + (size_t)(m0 + r) * 256 + kc + cq * 4);
    }
    __syncthreads();
    const float* Wrow = Wp + (size_t)(w * 16) * 256 + kc;
#pragma unroll 4
    for (int k = 0; k < 128; ++k) {
      float v = us[lane][k];
#pragma unroll
      for (int j = 0; j < 16; ++j)
        acc[j] = fmaf(v, Wrow[j * 256 + k], acc[j]);
    }
  }
  __syncthreads();
#pragma unroll
  for (int q = 0; q < 4; ++q)
    *(float4*)&xt[lane][w * 16 + q * 4] =
        make_float4(acc[q * 4], acc[q * 4 + 1], acc[q * 4 + 2], acc[q * 4 + 3]);
  __syncthreads();
  // LN stats: 8 threads per row
  {
    int r = tid >> 3, kq = (tid & 7) * 16;
    float s = 0.f, q = 0.f;
#pragma unroll 8
    for (int kk = 0; kk < 16; ++kk) {
      float v = xt[r][kq + kk];
      s += v; q = fmaf(v, v, q);
    }
    s += __shfl_xor(s, 1, 64); s += __shfl_xor(s, 2, 64);
    s += __shfl_xor(s, 4, 64);
    q += __shfl_xor(q, 1, 64); q += __shfl_xor(q, 2, 64);
    q += __shfl_xor(q, 4, 64);
    if ((tid & 7) == 0) {
      float mu = s * (1.f / 128.f);
      float var = q * (1.f / 128.f) - mu * mu;
      mus[r] = mu;
      invs[r] = rsqrtf(var + 1e-5f);
    }
  }
  __syncthreads();
  // LN + silu in-place
  for (int i = 0; i < 16; ++i) {
    int idx = tid + i * 512;
    int r = idx >> 7, k = idx & 127;
    float v = xt[r][k];
    float xn = (v - mus[r]) * invs[r] * gamma[k] + beta[k];
    xt[r][k] = xn / (1.f + __expf(-xn));
  }
  __syncthreads();
  // convout: lane = row; wave w owns 8 channels (wave-uniform s_loads)
  int cbase = w * 8;
  const float* Wrow2 = Wo + cbase * 128;
  float acc2[8];
#pragma unroll
  for (int j = 0; j < 8; ++j) acc2[j] = 0.f;
#pragma unroll 4
  for (int k = 0; k < 128; ++k) {
    float v = xt[lane][k];
#pragma unroll
    for (int j = 0; j < 8; ++j)
      acc2[j] = fmaf(v, Wrow2[j * 128 + k], acc2[j]);
  }
  int m = m0 + lane;
  int b = m >> 12, l = m & 4095;
#pragma unroll
  for (int j = 0; j < 8; ++j)
    out[((size_t)b * 64 + cbase + j) * 4096 + l] = acc2[j] + bo[cbase + j];
}

extern "C" void kernel_launch(void* const* d_in, const int* in_sizes, int n_in,
                              void* d_out, int out_size, void* d_ws, size_t ws_size,
                              hipStream_t stream) {
  (void)in_sizes; (void)n_in; (void)out_size; (void)ws_size;
  const float* x         = (const float*)d_in[0];
  const float* skip      = (const float*)d_in[1];
  const float* up_w      = (const float*)d_in[2];
  const float* up_b      = (const float*)d_in[3];
  const float* in_proj_w = (const float*)d_in[4];
  const float* conv1d_w  = (const float*)d_in[5];
  const float* conv1d_b  = (const float*)d_in[6];
  const float* x_proj_w  = (const float*)d_in[7];
  const float* dt_proj_w = (const float*)d_in[8];
  const float* dt_proj_b = (const float*)d_in[9];
  const float* A_log     = (const float*)d_in[10];
  const float* Dp        = (const float*)d_in[11];
  const float* out_proj_w= (const float*)d_in[12];
  const float* ln_gamma  = (const float*)d_in[13];
  const float* ln_beta   = (const float*)d_in[14];
  const float* convout_w = (const float*)d_in[15];
  const float* convout_b = (const float*)d_in[16];
  float* out = (float*)d_out;
  float* ws  = (float*)d_ws;

  // workspace layout (floats)
  float* seq    = ws;                  // 2,097,152
  float* xz     = ws + 2097152;        // 8,388,608
  float* u      = ws + 10485760;       // 4,194,304
  float* dbc    = ws + 14680064;       //   655,360
  float* y      = ws + 15335424;       // 4,194,304
  float* carryA = ws + 19529728;       // 2,097,152  (= 4*NC*256*16)
  float* carryH = ws + 21626880;       // 2,097,152

  upcat_kernel<<<256, 256, 0, stream>>>(x, skip, up_w, up_b, seq);
  inproj_kernel<<<dim3(16384 / 64, 4), 512, 0, stream>>>(seq, in_proj_w, xz);
  xproj_kernel<<<dim3(16384 / 64, 2), 256, 0, stream>>>(
      xz, conv1d_w, conv1d_b, x_proj_w, dbc, u);
  scan_pass1<<<4 * NC, 256, 0, stream>>>(u, dbc, A_log, dt_proj_w, dt_proj_b,
                                         carryA, carryH);
  scan_mid<<<256, 64, 0, stream>>>(carryA, carryH);
  scan_pass3<<<4 * NC, 256, 0, stream>>>(u, dbc, xz, A_log, dt_proj_w,
                                         dt_proj_b, Dp, carryH, y);
  fused_out_kernel<<<256, 512, 0, stream>>>(y, out_proj_w, ln_gamma, ln_beta,
                                            convout_w, convout_b, out);
}

// Round 15
// 202.933 us; speedup vs baseline: 1.1081x; 1.1081x over previous
//
#include <hip/hip_runtime.h>

#define L_SEQ 4096
#define DM 128
#define DIN 256
#define NC 128       // scan chunks
#define CHUNK 32     // L_SEQ / NC

// ---------------- K1: ConvTranspose2d(2x2,s2) + bias + concat -> seq (B,L,128)
__global__ __launch_bounds__(256) void upcat_kernel(
    const float* __restrict__ x, const float* __restrict__ skip,
    const float* __restrict__ up_w, const float* __restrict__ up_b,
    float* __restrict__ seq) {
  int b = blockIdx.x >> 6, hh = blockIdx.x & 63;
  int h = hh >> 1, i = hh & 1;
  int tid = threadIdx.x;
  __shared__ float xs[128][32];      // x[b][c][h][:]
  __shared__ float wsh[2][128][64];  // [j][c][o] for this i
  for (int e = tid; e < 1024; e += 256) {
    int c = e >> 3, q = e & 7;
    *(float4*)&xs[c][q * 4] =
        *(const float4*)(x + (((size_t)b * 128 + c) * 32 + h) * 32 + q * 4);
  }
  for (int e = tid; e < 8192; e += 256) {
    int c = e >> 6, o = e & 63;
    float2 v = *(const float2*)(up_w + c * 256 + o * 4 + i * 2);
    wsh[0][c][o] = v.x;
    wsh[1][c][o] = v.y;
  }
  __syncthreads();
  int tx = tid & 15, ty = tid >> 4;  // o-quad, ww-quad
  float4 bv = *(const float4*)(up_b + tx * 4);
  float acc[4][4];                   // [a -> ww=ty*4+a][o]
#pragma unroll
  for (int a = 0; a < 4; ++a) {
    acc[a][0] = bv.x; acc[a][1] = bv.y; acc[a][2] = bv.z; acc[a][3] = bv.w;
  }
#pragma unroll 4
  for (int c = 0; c < 128; ++c) {
    float x0 = xs[c][ty * 2];        // ww = 4ty+0,1  (w = 2ty)
    float x1 = xs[c][ty * 2 + 1];    // ww = 4ty+2,3  (w = 2ty+1)
    float4 w0 = *(const float4*)&wsh[0][c][tx * 4];
    float4 w1 = *(const float4*)&wsh[1][c][tx * 4];
    acc[0][0] = fmaf(x0, w0.x, acc[0][0]); acc[0][1] = fmaf(x0, w0.y, acc[0][1]);
    acc[0][2] = fmaf(x0, w0.z, acc[0][2]); acc[0][3] = fmaf(x0, w0.w, acc[0][3]);
    acc[1][0] = fmaf(x0, w1.x, acc[1][0]); acc[1][1] = fmaf(x0, w1.y, acc[1][1]);
    acc[1][2] = fmaf(x0, w1.z, acc[1][2]); acc[1][3] = fmaf(x0, w1.w, acc[1][3]);
    acc[2][0] = fmaf(x1, w0.x, acc[2][0]); acc[2][1] = fmaf(x1, w0.y, acc[2][1]);
    acc[2][2] = fmaf(x1, w0.z, acc[2][2]); acc[2][3] = fmaf(x1, w0.w, acc[2][3]);
    acc[3][0] = fmaf(x1, w1.x, acc[3][0]); acc[3][1] = fmaf(x1, w1.y, acc[3][1]);
    acc[3][2] = fmaf(x1, w1.z, acc[3][2]); acc[3][3] = fmaf(x1, w1.w, acc[3][3]);
  }
  size_t mrow_base = (size_t)b * L_SEQ + (size_t)hh * 64;
#pragma unroll
  for (int a = 0; a < 4; ++a) {
    int ww = ty * 4 + a;
    *(float4*)(seq + (mrow_base + ww) * DM + tx * 4) =
        make_float4(acc[a][0], acc[a][1], acc[a][2], acc[a][3]);
  }
  // skip half: channels 64..127
  for (int e = tid; e < 4096; e += 256) {
    int c = e & 63, ww = e >> 6;
    seq[(mrow_base + ww) * DM + 64 + c] =
        skip[((size_t)b * 64 + c) * (size_t)L_SEQ + hh * 64 + ww];
  }
}

// ---------------- K2: in_proj GEMM, 128x128 tile, 8x8 acc/thread.
// 64 FMA per 4 ds_read_b128 (2 FLOP/B) = LDS/VALU balance point.
// Cols split {tx*4, 64+tx*4}: 16 addrs @ 4-dword stride -> 2/bank (free).
__global__ __launch_bounds__(256) void inproj_gemm(
    const float* __restrict__ A, const float* __restrict__ W,
    float* __restrict__ C) {
  __shared__ float As[32][132];  // [k][m]
  __shared__ float Ws[32][132];  // [k][n]
  int m0 = blockIdx.x * 128, n0 = blockIdx.y * 128;
  int tid = threadIdx.x;
  int tx = tid & 15, ty = tid >> 4;
  float acc[8][8];
#pragma unroll
  for (int a = 0; a < 8; ++a)
#pragma unroll
    for (int bb = 0; bb < 8; ++bb) acc[a][bb] = 0.f;

  for (int k0 = 0; k0 < 128; k0 += 32) {
    __syncthreads();
    for (int e = tid; e < 1024; e += 256) {
      int r = e >> 3, c4 = (e & 7) << 2;
      float4 va = *(const float4*)(A + (size_t)(m0 + r) * 128 + k0 + c4);
      As[c4 + 0][r] = va.x; As[c4 + 1][r] = va.y;
      As[c4 + 2][r] = va.z; As[c4 + 3][r] = va.w;
      float4 vw = *(const float4*)(W + (size_t)(n0 + r) * 128 + k0 + c4);
      Ws[c4 + 0][r] = vw.x; Ws[c4 + 1][r] = vw.y;
      Ws[c4 + 2][r] = vw.z; Ws[c4 + 3][r] = vw.w;
    }
    __syncthreads();
#pragma unroll
    for (int kk = 0; kk < 32; ++kk) {
      float4 a0 = *(const float4*)&As[kk][ty * 4];
      float4 a1 = *(const float4*)&As[kk][ty * 4 + 64];
      float4 w0 = *(const float4*)&Ws[kk][tx * 4];
      float4 w1 = *(const float4*)&Ws[kk][tx * 4 + 64];
      float a_[8] = {a0.x, a0.y, a0.z, a0.w, a1.x, a1.y, a1.z, a1.w};
      float w_[8] = {w0.x, w0.y, w0.z, w0.w, w1.x, w1.y, w1.z, w1.w};
#pragma unroll
      for (int a = 0; a < 8; ++a)
#pragma unroll
        for (int bb = 0; bb < 8; ++bb)
          acc[a][bb] = fmaf(a_[a], w_[bb], acc[a][bb]);
    }
  }
#pragma unroll
  for (int a = 0; a < 8; ++a) {
    int row = m0 + ((a < 4) ? (ty * 4 + a) : (64 + ty * 4 + a - 4));
    *(float4*)(C + (size_t)row * 512 + n0 + tx * 4) =
        make_float4(acc[a][0], acc[a][1], acc[a][2], acc[a][3]);
    *(float4*)(C + (size_t)row * 512 + n0 + 64 + tx * 4) =
        make_float4(acc[a][4], acc[a][5], acc[a][6], acc[a][7]);
  }
}

// ---------------- generic fp32 GEMM: 64x64 tile (out_proj)
__global__ __launch_bounds__(256) void gemm_bt(
    const float* __restrict__ A, const float* __restrict__ W,
    float* __restrict__ C, int M, int N, int K) {
  __shared__ float As[32][68];  // [k][m], pad 68
  __shared__ float Ws[32][68];  // [k][n]
  int m0 = blockIdx.x * 64, n0 = blockIdx.y * 64;
  int tid = threadIdx.x;
  int tx = tid & 15, ty = tid >> 4;
  float acc[4][4];
#pragma unroll
  for (int a = 0; a < 4; ++a)
#pragma unroll
    for (int bb = 0; bb < 4; ++bb) acc[a][bb] = 0.f;

  for (int k0 = 0; k0 < K; k0 += 32) {
    __syncthreads();
    for (int e = tid; e < 512; e += 256) {
      int r = e >> 3;
      int c4 = (e & 7) << 2;
      float4 va = *(const float4*)(A + (size_t)(m0 + r) * K + k0 + c4);
      As[c4 + 0][r] = va.x; As[c4 + 1][r] = va.y;
      As[c4 + 2][r] = va.z; As[c4 + 3][r] = va.w;
      float4 vw = *(const float4*)(W + (size_t)(n0 + r) * K + k0 + c4);
      Ws[c4 + 0][r] = vw.x; Ws[c4 + 1][r] = vw.y;
      Ws[c4 + 2][r] = vw.z; Ws[c4 + 3][r] = vw.w;
    }
    __syncthreads();
#pragma unroll
    for (int kk = 0; kk < 32; ++kk) {
      float4 av = *(const float4*)(&As[kk][ty * 4]);
      float4 wv = *(const float4*)(&Ws[kk][tx * 4]);
      float av_[4] = {av.x, av.y, av.z, av.w};
      float wv_[4] = {wv.x, wv.y, wv.z, wv.w};
#pragma unroll
      for (int a = 0; a < 4; ++a)
#pragma unroll
        for (int bb = 0; bb < 4; ++bb)
          acc[a][bb] = fmaf(av_[a], wv_[bb], acc[a][bb]);
    }
  }
#pragma unroll
  for (int a = 0; a < 4; ++a)
#pragma unroll
    for (int bb = 0; bb < 4; ++bb)
      C[(size_t)(m0 + ty * 4 + a) * N + n0 + tx * 4 + bb] = acc[a][bb];
}

// ---------------- K4: fused conv1d+silu+xproj: xz -> u (global), dbc
__global__ __launch_bounds__(256) void xproj_kernel(
    const float* __restrict__ xz, const float* __restrict__ cw,
    const float* __restrict__ cb, const float* __restrict__ W,
    float* __restrict__ dbc, float* __restrict__ u_out) {
  __shared__ float xzt[67][64];  // raw xz rows (m0-3+rr)
  __shared__ float us[64][68];   // silu(conv(xz)) = u tile, pad 68
  int m0 = blockIdx.x * 64;
  int tid = threadIdx.x;
  int lane = tid & 63;
  int w = __builtin_amdgcn_readfirstlane(tid >> 6);  // wave-uniform 0..3
  int jbase = blockIdx.y * 20 + w * 5;
  const float* Wb = W + jbase * 256;
  bool first = (m0 & (L_SEQ - 1)) == 0;  // block at sequence start
  int cc4 = (tid & 15) << 2;             // conv-phase column group
  int r0 = tid >> 4;                     // conv-phase row base
  float acc[5];
#pragma unroll
  for (int j = 0; j < 5; ++j) acc[j] = 0.f;
  for (int k0 = 0; k0 < 256; k0 += 64) {
    __syncthreads();
    for (int e = tid; e < 67 * 16; e += 256) {
      int rr = e >> 4, c4 = (e & 15) << 2;
      float4 v;
      if (first && rr < 3)
        v = make_float4(0.f, 0.f, 0.f, 0.f);
      else
        v = *(const float4*)(xz + (size_t)(m0 - 3 + rr) * 512 + k0 + c4);
      *(float4*)&xzt[rr][c4] = v;
    }
    __syncthreads();
    {
      int d = k0 + cc4;
      float4 cw0 = *(const float4*)(cw + (d + 0) * 4);
      float4 cw1 = *(const float4*)(cw + (d + 1) * 4);
      float4 cw2 = *(const float4*)(cw + (d + 2) * 4);
      float4 cw3 = *(const float4*)(cw + (d + 3) * 4);
      float4 cbv = *(const float4*)(cb + d);
#pragma unroll
      for (int s = 0; s < 4; ++s) {
        int r = r0 + s * 16;
        float a0 = cbv.x, a1 = cbv.y, a2 = cbv.z, a3 = cbv.w;
        a0 = fmaf(xzt[r + 0][cc4 + 0], cw0.x, a0);
        a0 = fmaf(xzt[r + 1][cc4 + 0], cw0.y, a0);
        a0 = fmaf(xzt[r + 2][cc4 + 0], cw0.z, a0);
        a0 = fmaf(xzt[r + 3][cc4 + 0], cw0.w, a0);
        a1 = fmaf(xzt[r + 0][cc4 + 1], cw1.x, a1);
        a1 = fmaf(xzt[r + 1][cc4 + 1], cw1.y, a1);
        a1 = fmaf(xzt[r + 2][cc4 + 1], cw1.z, a1);
        a1 = fmaf(xzt[r + 3][cc4 + 1], cw1.w, a1);
        a2 = fmaf(xzt[r + 0][cc4 + 2], cw2.x, a2);
        a2 = fmaf(xzt[r + 1][cc4 + 2], cw2.y, a2);
        a2 = fmaf(xzt[r + 2][cc4 + 2], cw2.z, a2);
        a2 = fmaf(xzt[r + 3][cc4 + 2], cw2.w, a2);
        a3 = fmaf(xzt[r + 0][cc4 + 3], cw3.x, a3);
        a3 = fmaf(xzt[r + 1][cc4 + 3], cw3.y, a3);
        a3 = fmaf(xzt[r + 2][cc4 + 3], cw3.z, a3);
        a3 = fmaf(xzt[r + 3][cc4 + 3], cw3.w, a3);
        float o0 = a0 / (1.f + __expf(-a0));
        float o1 = a1 / (1.f + __expf(-a1));
        float o2 = a2 / (1.f + __expf(-a2));
        float o3 = a3 / (1.f + __expf(-a3));
        *(float4*)&us[r][cc4] = make_float4(o0, o1, o2, o3);
        if (blockIdx.y == 0)
          *(float4*)(u_out + (size_t)(m0 + r) * 256 + d) =
              make_float4(o0, o1, o2, o3);
      }
    }
    __syncthreads();
#pragma unroll
    for (int kk = 0; kk < 64; kk += 4) {
      float4 a4 = *(const float4*)&us[lane][kk];
      float a_[4] = {a4.x, a4.y, a4.z, a4.w};
#pragma unroll
      for (int i = 0; i < 4; ++i)
#pragma unroll
        for (int j = 0; j < 5; ++j)
          acc[j] = fmaf(a_[i], Wb[j * 256 + k0 + kk + i], acc[j]);
    }
  }
  size_t base = (size_t)(m0 + lane) * 40 + jbase;
#pragma unroll
  for (int j = 0; j < 5; ++j) dbc[base + j] = acc[j];
}

// ---------------- K5: chunked parallel selective scan ----------------
__device__ __forceinline__ float softplus_f(float a) {
  return (a > 20.f) ? a : log1pf(__expf(a));
}

__global__ __launch_bounds__(256) void scan_pass1(
    const float* __restrict__ u, const float* __restrict__ dbc,
    const float* __restrict__ A_log, const float* __restrict__ Wdt,
    const float* __restrict__ bdt, float* __restrict__ carryA,
    float* __restrict__ carryH) {
  int bid = blockIdx.x;          // b*NC + c
  int b = bid >> 7;
  int c = bid & (NC - 1);
  int d = threadIdx.x;
  __shared__ float ls[CHUNK * 40];
  size_t l0 = (size_t)b * L_SEQ + (size_t)c * CHUNK;
  const float* rp = dbc + l0 * 40;
  for (int e = d; e < CHUNK * 40; e += 256) ls[e] = rp[e];
  float Ac[16];
  {
    const float4* ar = (const float4*)(A_log + d * 16);
#pragma unroll
    for (int q = 0; q < 4; ++q) {
      float4 v = ar[q];
      Ac[q * 4 + 0] = -__expf(v.x); Ac[q * 4 + 1] = -__expf(v.y);
      Ac[q * 4 + 2] = -__expf(v.z); Ac[q * 4 + 3] = -__expf(v.w);
    }
  }
  float wdt[8];
  {
    const float4* wr = (const float4*)(Wdt + d * 8);
    float4 v0 = wr[0], v1 = wr[1];
    wdt[0] = v0.x; wdt[1] = v0.y; wdt[2] = v0.z; wdt[3] = v0.w;
    wdt[4] = v1.x; wdt[5] = v1.y; wdt[6] = v1.z; wdt[7] = v1.w;
  }
  float bdt_v = bdt[d];
  const float* up = u + l0 * 256 + d;
  __syncthreads();
  float h[16];
#pragma unroll
  for (int n = 0; n < 16; ++n) h[n] = 0.f;
  float dvs = 0.f;
#pragma unroll 4
  for (int li = 0; li < CHUNK; ++li) {
    float uv = up[(size_t)li * 256];
    float acc = bdt_v;
#pragma unroll
    for (int j = 0; j < 8; ++j)
      acc = fmaf(ls[li * 40 + j], wdt[j], acc);
    float dv = softplus_f(acc);
    dvs += dv;
    float t = dv * uv;
#pragma unroll
    for (int n = 0; n < 16; ++n) {
      float dA = __expf(dv * Ac[n]);
      h[n] = fmaf(dA, h[n], t * ls[li * 40 + 8 + n]);
    }
  }
  float4* cA = (float4*)(carryA + ((size_t)bid * 256 + d) * 16);
  float4* cH = (float4*)(carryH + ((size_t)bid * 256 + d) * 16);
#pragma unroll
  for (int q = 0; q < 4; ++q) {
    // prod of dA over chunk == exp(sum(dv) * Ac)
    cA[q] = make_float4(__expf(dvs * Ac[q * 4]), __expf(dvs * Ac[q * 4 + 1]),
                        __expf(dvs * Ac[q * 4 + 2]), __expf(dvs * Ac[q * 4 + 3]));
    cH[q] = make_float4(h[q * 4], h[q * 4 + 1], h[q * 4 + 2], h[q * 4 + 3]);
  }
}

__global__ __launch_bounds__(64) void scan_mid(
    const float* __restrict__ carryA, float* __restrict__ carryH) {
  int gid = blockIdx.x * 64 + threadIdx.x;  // 16384 chains
  int b = gid >> 12;
  int dn = gid & 4095;
  size_t i = ((size_t)(b * NC) << 12) + dn;
  float h = 0.f;
  float a = carryA[i], hl = carryH[i];
#pragma unroll 4
  for (int c = 0; c < NC - 1; ++c) {
    size_t i2 = i + 4096;
    float a2 = carryA[i2];
    float hl2 = carryH[i2];
    carryH[i] = h;                 // h entering chunk c
    h = fmaf(a, h, hl);
    a = a2; hl = hl2; i = i2;
  }
  carryH[i] = h;                   // h entering last chunk
}

__global__ __launch_bounds__(256) void scan_pass3(
    const float* __restrict__ u, const float* __restrict__ dbc,
    const float* __restrict__ xz, const float* __restrict__ A_log,
    const float* __restrict__ Wdt, const float* __restrict__ bdt,
    const float* __restrict__ Dp, const float* __restrict__ carryH,
    float* __restrict__ y) {
  int bid = blockIdx.x;
  int b = bid >> 7;
  int c = bid & (NC - 1);
  int d = threadIdx.x;
  __shared__ float ls[CHUNK * 40];
  size_t l0 = (size_t)b * L_SEQ + (size_t)c * CHUNK;
  const float* rp = dbc + l0 * 40;
  for (int e = d; e < CHUNK * 40; e += 256) ls[e] = rp[e];
  float Ac[16];
  {
    const float4* ar = (const float4*)(A_log + d * 16);
#pragma unroll
    for (int q = 0; q < 4; ++q) {
      float4 v = ar[q];
      Ac[q * 4 + 0] = -__expf(v.x); Ac[q * 4 + 1] = -__expf(v.y);
      Ac[q * 4 + 2] = -__expf(v.z); Ac[q * 4 + 3] = -__expf(v.w);
    }
  }
  float wdt[8];
  {
    const float4* wr = (const float4*)(Wdt + d * 8);
    float4 v0 = wr[0], v1 = wr[1];
    wdt[0] = v0.x; wdt[1] = v0.y; wdt[2] = v0.z; wdt[3] = v0.w;
    wdt[4] = v1.x; wdt[5] = v1.y; wdt[6] = v1.z; wdt[7] = v1.w;
  }
  float bdt_v = bdt[d];
  float Dv = Dp[d];
  float h[16];
  {
    const float4* cH = (const float4*)(carryH + ((size_t)bid * 256 + d) * 16);
#pragma unroll
    for (int q = 0; q < 4; ++q) {
      float4 v = cH[q];
      h[q * 4 + 0] = v.x; h[q * 4 + 1] = v.y;
      h[q * 4 + 2] = v.z; h[q * 4 + 3] = v.w;
    }
  }
  const float* up = u + l0 * 256 + d;
  const float* zp = xz + l0 * 512 + 256 + d;
  float* yp = y + l0 * 256 + d;
  __syncthreads();
#pragma unroll 4
  for (int li = 0; li < CHUNK; ++li) {
    float uv = up[(size_t)li * 256];
    float zv = zp[(size_t)li * 512];
    float acc = bdt_v;
#pragma unroll
    for (int j = 0; j < 8; ++j)
      acc = fmaf(ls[li * 40 + j], wdt[j], acc);
    float dv = softplus_f(acc);
    float t = dv * uv;
    float p = 0.f;
#pragma unroll
    for (int n = 0; n < 16; ++n) {
      float dA = __expf(dv * Ac[n]);
      h[n] = fmaf(dA, h[n], t * ls[li * 40 + 8 + n]);
      p = fmaf(h[n], ls[li * 40 + 24 + n], p);
    }
    float s = zv / (1.f + __expf(-zv));
    yp[(size_t)li * 256] = (p + uv * Dv) * s;
  }
}

// ---------------- K6: LayerNorm(ch) + silu + 1x1 conv -> out (B,64,H2,W2)
__global__ __launch_bounds__(256) void ln_out_kernel(
    const float* __restrict__ s2, const float* __restrict__ gamma,
    const float* __restrict__ beta, const float* __restrict__ Wo,
    const float* __restrict__ bo, float* __restrict__ out) {
  __shared__ float xt[64][129];
  __shared__ float mus[64], invs[64];
  int tid = threadIdx.x;
  int m0 = blockIdx.x * 64;
  // Phase A: coalesced tile load -> LDS
  for (int i = 0; i < 8; ++i) {
    int s = tid + i * 256;          // 2048 float4 slots
    int r = s >> 5, q = s & 31;
    float4 v = *(const float4*)(s2 + (size_t)(m0 + r) * 128 + q * 4);
    xt[r][q * 4 + 0] = v.x; xt[r][q * 4 + 1] = v.y;
    xt[r][q * 4 + 2] = v.z; xt[r][q * 4 + 3] = v.w;
  }
  __syncthreads();
  // Phase B: stats, 4 threads per row
  {
    int r = tid >> 2, kq = (tid & 3) * 32;
    float s = 0.f, q = 0.f;
#pragma unroll 8
    for (int kk = 0; kk < 32; ++kk) {
      float v = xt[r][kq + kk];
      s += v; q = fmaf(v, v, q);
    }
    s += __shfl_xor(s, 1, 64); s += __shfl_xor(s, 2, 64);
    q += __shfl_xor(q, 1, 64); q += __shfl_xor(q, 2, 64);
    if ((tid & 3) == 0) {
      float mu = s * (1.f / 128.f);
      float var = q * (1.f / 128.f) - mu * mu;
      mus[r] = mu;
      invs[r] = rsqrtf(var + 1e-5f);
    }
  }
  __syncthreads();
  // Phase T: LN + silu in-place
  for (int i = 0; i < 32; ++i) {
    int idx = tid + i * 256;        // 8192 elements
    int r = idx >> 7, k = idx & 127;
    float v = xt[r][k];
    float xn = (v - mus[r]) * invs[r] * gamma[k] + beta[k];
    xt[r][k] = xn / (1.f + __expf(-xn));
  }
  __syncthreads();
  // Phase C: GEMM, lane = row, wave-uniform channels
  int lane = tid & 63;
  int w = __builtin_amdgcn_readfirstlane(tid >> 6);
  int cbase = blockIdx.y * 32 + w * 8;
  const float* Wrow = Wo + cbase * 128;
  float acc[8];
#pragma unroll
  for (int j = 0; j < 8; ++j) acc[j] = 0.f;
#pragma unroll 4
  for (int k = 0; k < 128; ++k) {
    float v = xt[lane][k];
#pragma unroll
    for (int j = 0; j < 8; ++j)
      acc[j] = fmaf(v, Wrow[j * 128 + k], acc[j]);
  }
  int m = m0 + lane;
  int b = m >> 12, l = m & 4095;
#pragma unroll
  for (int j = 0; j < 8; ++j)
    out[((size_t)b * 64 + cbase + j) * 4096 + l] = acc[j] + bo[cbase + j];
}

extern "C" void kernel_launch(void* const* d_in, const int* in_sizes, int n_in,
                              void* d_out, int out_size, void* d_ws, size_t ws_size,
                              hipStream_t stream) {
  (void)in_sizes; (void)n_in; (void)out_size; (void)ws_size;
  const float* x         = (const float*)d_in[0];
  const float* skip      = (const float*)d_in[1];
  const float* up_w      = (const float*)d_in[2];
  const float* up_b      = (const float*)d_in[3];
  const float* in_proj_w = (const float*)d_in[4];
  const float* conv1d_w  = (const float*)d_in[5];
  const float* conv1d_b  = (const float*)d_in[6];
  const float* x_proj_w  = (const float*)d_in[7];
  const float* dt_proj_w = (const float*)d_in[8];
  const float* dt_proj_b = (const float*)d_in[9];
  const float* A_log     = (const float*)d_in[10];
  const float* Dp        = (const float*)d_in[11];
  const float* out_proj_w= (const float*)d_in[12];
  const float* ln_gamma  = (const float*)d_in[13];
  const float* ln_beta   = (const float*)d_in[14];
  const float* convout_w = (const float*)d_in[15];
  const float* convout_b = (const float*)d_in[16];
  float* out = (float*)d_out;
  float* ws  = (float*)d_ws;

  // workspace layout (floats)
  float* seq    = ws;                  // 2,097,152  (reused as s2 after out_proj)
  float* xz     = ws + 2097152;        // 8,388,608
  float* u      = ws + 10485760;       // 4,194,304
  float* dbc    = ws + 14680064;       //   655,360
  float* y      = ws + 15335424;       // 4,194,304
  float* carryA = ws + 19529728;       // 2,097,152  (= 4*NC*256*16)
  float* carryH = ws + 21626880;       // 2,097,152

  upcat_kernel<<<256, 256, 0, stream>>>(x, skip, up_w, up_b, seq);
  inproj_gemm<<<dim3(16384 / 128, 512 / 128), 256, 0, stream>>>(seq, in_proj_w,
                                                                xz);
  xproj_kernel<<<dim3(16384 / 64, 2), 256, 0, stream>>>(
      xz, conv1d_w, conv1d_b, x_proj_w, dbc, u);
  scan_pass1<<<4 * NC, 256, 0, stream>>>(u, dbc, A_log, dt_proj_w, dt_proj_b,
                                         carryA, carryH);
  scan_mid<<<256, 64, 0, stream>>>(carryA, carryH);
  scan_pass3<<<4 * NC, 256, 0, stream>>>(u, dbc, xz, A_log, dt_proj_w,
                                         dt_proj_b, Dp, carryH, y);
  gemm_bt<<<dim3(16384 / 64, 128 / 64), 256, 0, stream>>>(y, out_proj_w, seq,
                                                          16384, 128, 256);
  ln_out_kernel<<<dim3(256, 2), 256, 0, stream>>>(seq, ln_gamma, ln_beta,
                                                  convout_w, convout_b, out);
}

// Round 16
// 201.683 us; speedup vs baseline: 1.1150x; 1.0062x over previous
//
#include <hip/hip_runtime.h>

#define L_SEQ 4096
#define DM 128
#define DIN 256
#define NC 128       // scan chunks
#define CHUNK 32     // L_SEQ / NC

// ---------------- K1: ConvTranspose2d(2x2,s2) + bias + concat -> seq (B,L,128)
__global__ __launch_bounds__(256) void upcat_kernel(
    const float* __restrict__ x, const float* __restrict__ skip,
    const float* __restrict__ up_w, const float* __restrict__ up_b,
    float* __restrict__ seq) {
  int b = blockIdx.x >> 6, hh = blockIdx.x & 63;
  int h = hh >> 1, i = hh & 1;
  int tid = threadIdx.x;
  __shared__ float xs[128][32];      // x[b][c][h][:]
  __shared__ float wsh[2][128][64];  // [j][c][o] for this i
  for (int e = tid; e < 1024; e += 256) {
    int c = e >> 3, q = e & 7;
    *(float4*)&xs[c][q * 4] =
        *(const float4*)(x + (((size_t)b * 128 + c) * 32 + h) * 32 + q * 4);
  }
  for (int e = tid; e < 8192; e += 256) {
    int c = e >> 6, o = e & 63;
    float2 v = *(const float2*)(up_w + c * 256 + o * 4 + i * 2);
    wsh[0][c][o] = v.x;
    wsh[1][c][o] = v.y;
  }
  __syncthreads();
  int tx = tid & 15, ty = tid >> 4;  // o-quad, ww-quad
  float4 bv = *(const float4*)(up_b + tx * 4);
  float acc[4][4];                   // [a -> ww=ty*4+a][o]
#pragma unroll
  for (int a = 0; a < 4; ++a) {
    acc[a][0] = bv.x; acc[a][1] = bv.y; acc[a][2] = bv.z; acc[a][3] = bv.w;
  }
#pragma unroll 4
  for (int c = 0; c < 128; ++c) {
    float x0 = xs[c][ty * 2];        // ww = 4ty+0,1  (w = 2ty)
    float x1 = xs[c][ty * 2 + 1];    // ww = 4ty+2,3  (w = 2ty+1)
    float4 w0 = *(const float4*)&wsh[0][c][tx * 4];
    float4 w1 = *(const float4*)&wsh[1][c][tx * 4];
    acc[0][0] = fmaf(x0, w0.x, acc[0][0]); acc[0][1] = fmaf(x0, w0.y, acc[0][1]);
    acc[0][2] = fmaf(x0, w0.z, acc[0][2]); acc[0][3] = fmaf(x0, w0.w, acc[0][3]);
    acc[1][0] = fmaf(x0, w1.x, acc[1][0]); acc[1][1] = fmaf(x0, w1.y, acc[1][1]);
    acc[1][2] = fmaf(x0, w1.z, acc[1][2]); acc[1][3] = fmaf(x0, w1.w, acc[1][3]);
    acc[2][0] = fmaf(x1, w0.x, acc[2][0]); acc[2][1] = fmaf(x1, w0.y, acc[2][1]);
    acc[2][2] = fmaf(x1, w0.z, acc[2][2]); acc[2][3] = fmaf(x1, w0.w, acc[2][3]);
    acc[3][0] = fmaf(x1, w1.x, acc[3][0]); acc[3][1] = fmaf(x1, w1.y, acc[3][1]);
    acc[3][2] = fmaf(x1, w1.z, acc[3][2]); acc[3][3] = fmaf(x1, w1.w, acc[3][3]);
  }
  size_t mrow_base = (size_t)b * L_SEQ + (size_t)hh * 64;
#pragma unroll
  for (int a = 0; a < 4; ++a) {
    int ww = ty * 4 + a;
    *(float4*)(seq + (mrow_base + ww) * DM + tx * 4) =
        make_float4(acc[a][0], acc[a][1], acc[a][2], acc[a][3]);
  }
  // skip half: channels 64..127
  for (int e = tid; e < 4096; e += 256) {
    int c = e & 63, ww = e >> 6;
    seq[(mrow_base + ww) * DM + 64 + c] =
        skip[((size_t)b * 64 + c) * (size_t)L_SEQ + hh * 64 + ww];
  }
}

// ---------------- fp32 GEMM, 128x64 tile, 8x4 acc/thread (in_proj)
__global__ __launch_bounds__(256) void gemm_bt128(
    const float* __restrict__ A, const float* __restrict__ W,
    float* __restrict__ C, int M, int N, int K) {
  __shared__ float As[32][132];  // [k][m], pad 132
  __shared__ float Ws[32][68];   // [k][n], pad 68
  int m0 = blockIdx.x * 128, n0 = blockIdx.y * 64;
  int tid = threadIdx.x;
  int tx = tid & 15, ty = tid >> 4;
  float acc[8][4];
#pragma unroll
  for (int a = 0; a < 8; ++a)
#pragma unroll
    for (int bb = 0; bb < 4; ++bb) acc[a][bb] = 0.f;

  for (int k0 = 0; k0 < K; k0 += 32) {
    __syncthreads();
    for (int e = tid; e < 1024; e += 256) {
      int r = e >> 3, c4 = (e & 7) << 2;
      float4 va = *(const float4*)(A + (size_t)(m0 + r) * K + k0 + c4);
      As[c4 + 0][r] = va.x; As[c4 + 1][r] = va.y;
      As[c4 + 2][r] = va.z; As[c4 + 3][r] = va.w;
    }
    for (int e = tid; e < 512; e += 256) {
      int r = e >> 3, c4 = (e & 7) << 2;
      float4 vw = *(const float4*)(W + (size_t)(n0 + r) * K + k0 + c4);
      Ws[c4 + 0][r] = vw.x; Ws[c4 + 1][r] = vw.y;
      Ws[c4 + 2][r] = vw.z; Ws[c4 + 3][r] = vw.w;
    }
    __syncthreads();
#pragma unroll
    for (int kk = 0; kk < 32; ++kk) {
      float4 a0 = *(const float4*)(&As[kk][ty * 8]);
      float4 a1 = *(const float4*)(&As[kk][ty * 8 + 4]);
      float4 wv = *(const float4*)(&Ws[kk][tx * 4]);
      float a_[8] = {a0.x, a0.y, a0.z, a0.w, a1.x, a1.y, a1.z, a1.w};
      float w_[4] = {wv.x, wv.y, wv.z, wv.w};
#pragma unroll
      for (int a = 0; a < 8; ++a)
#pragma unroll
        for (int bb = 0; bb < 4; ++bb)
          acc[a][bb] = fmaf(a_[a], w_[bb], acc[a][bb]);
    }
  }
#pragma unroll
  for (int a = 0; a < 8; ++a)
#pragma unroll
    for (int bb = 0; bb < 4; ++bb)
      C[(size_t)(m0 + ty * 8 + a) * N + n0 + tx * 4 + bb] = acc[a][bb];
}

// ---------------- generic fp32 GEMM: 64x64 tile (out_proj)
__global__ __launch_bounds__(256) void gemm_bt(
    const float* __restrict__ A, const float* __restrict__ W,
    float* __restrict__ C, int M, int N, int K) {
  __shared__ float As[32][68];  // [k][m], pad 68
  __shared__ float Ws[32][68];  // [k][n]
  int m0 = blockIdx.x * 64, n0 = blockIdx.y * 64;
  int tid = threadIdx.x;
  int tx = tid & 15, ty = tid >> 4;
  float acc[4][4];
#pragma unroll
  for (int a = 0; a < 4; ++a)
#pragma unroll
    for (int bb = 0; bb < 4; ++bb) acc[a][bb] = 0.f;

  for (int k0 = 0; k0 < K; k0 += 32) {
    __syncthreads();
    for (int e = tid; e < 512; e += 256) {
      int r = e >> 3;
      int c4 = (e & 7) << 2;
      float4 va = *(const float4*)(A + (size_t)(m0 + r) * K + k0 + c4);
      As[c4 + 0][r] = va.x; As[c4 + 1][r] = va.y;
      As[c4 + 2][r] = va.z; As[c4 + 3][r] = va.w;
      float4 vw = *(const float4*)(W + (size_t)(n0 + r) * K + k0 + c4);
      Ws[c4 + 0][r] = vw.x; Ws[c4 + 1][r] = vw.y;
      Ws[c4 + 2][r] = vw.z; Ws[c4 + 3][r] = vw.w;
    }
    __syncthreads();
#pragma unroll
    for (int kk = 0; kk < 32; ++kk) {
      float4 av = *(const float4*)(&As[kk][ty * 4]);
      float4 wv = *(const float4*)(&Ws[kk][tx * 4]);
      float av_[4] = {av.x, av.y, av.z, av.w};
      float wv_[4] = {wv.x, wv.y, wv.z, wv.w};
#pragma unroll
      for (int a = 0; a < 4; ++a)
#pragma unroll
        for (int bb = 0; bb < 4; ++bb)
          acc[a][bb] = fmaf(av_[a], wv_[bb], acc[a][bb]);
    }
  }
#pragma unroll
  for (int a = 0; a < 4; ++a)
#pragma unroll
    for (int bb = 0; bb < 4; ++bb)
      C[(size_t)(m0 + ty * 4 + a) * N + n0 + tx * 4 + bb] = acc[a][bb];
}

// ---------------- K4: fused conv1d+silu+xproj: xz -> u (global), dbc
__global__ __launch_bounds__(256) void xproj_kernel(
    const float* __restrict__ xz, const float* __restrict__ cw,
    const float* __restrict__ cb, const float* __restrict__ W,
    float* __restrict__ dbc, float* __restrict__ u_out) {
  __shared__ float xzt[67][64];  // raw xz rows (m0-3+rr)
  __shared__ float us[64][68];   // silu(conv(xz)) = u tile, pad 68
  int m0 = blockIdx.x * 64;
  int tid = threadIdx.x;
  int lane = tid & 63;
  int w = __builtin_amdgcn_readfirstlane(tid >> 6);  // wave-uniform 0..3
  int jbase = blockIdx.y * 20 + w * 5;
  const float* Wb = W + jbase * 256;
  bool first = (m0 & (L_SEQ - 1)) == 0;  // block at sequence start
  int cc4 = (tid & 15) << 2;             // conv-phase column group
  int r0 = tid >> 4;                     // conv-phase row base
  float acc[5];
#pragma unroll
  for (int j = 0; j < 5; ++j) acc[j] = 0.f;
  for (int k0 = 0; k0 < 256; k0 += 64) {
    __syncthreads();
    for (int e = tid; e < 67 * 16; e += 256) {
      int rr = e >> 4, c4 = (e & 15) << 2;
      float4 v;
      if (first && rr < 3)
        v = make_float4(0.f, 0.f, 0.f, 0.f);
      else
        v = *(const float4*)(xz + (size_t)(m0 - 3 + rr) * 512 + k0 + c4);
      *(float4*)&xzt[rr][c4] = v;
    }
    __syncthreads();
    {
      int d = k0 + cc4;
      float4 cw0 = *(const float4*)(cw + (d + 0) * 4);
      float4 cw1 = *(const float4*)(cw + (d + 1) * 4);
      float4 cw2 = *(const float4*)(cw + (d + 2) * 4);
      float4 cw3 = *(const float4*)(cw + (d + 3) * 4);
      float4 cbv = *(const float4*)(cb + d);
#pragma unroll
      for (int s = 0; s < 4; ++s) {
        int r = r0 + s * 16;
        float a0 = cbv.x, a1 = cbv.y, a2 = cbv.z, a3 = cbv.w;
        a0 = fmaf(xzt[r + 0][cc4 + 0], cw0.x, a0);
        a0 = fmaf(xzt[r + 1][cc4 + 0], cw0.y, a0);
        a0 = fmaf(xzt[r + 2][cc4 + 0], cw0.z, a0);
        a0 = fmaf(xzt[r + 3][cc4 + 0], cw0.w, a0);
        a1 = fmaf(xzt[r + 0][cc4 + 1], cw1.x, a1);
        a1 = fmaf(xzt[r + 1][cc4 + 1], cw1.y, a1);
        a1 = fmaf(xzt[r + 2][cc4 + 1], cw1.z, a1);
        a1 = fmaf(xzt[r + 3][cc4 + 1], cw1.w, a1);
        a2 = fmaf(xzt[r + 0][cc4 + 2], cw2.x, a2);
        a2 = fmaf(xzt[r + 1][cc4 + 2], cw2.y, a2);
        a2 = fmaf(xzt[r + 2][cc4 + 2], cw2.z, a2);
        a2 = fmaf(xzt[r + 3][cc4 + 2], cw2.w, a2);
        a3 = fmaf(xzt[r + 0][cc4 + 3], cw3.x, a3);
        a3 = fmaf(xzt[r + 1][cc4 + 3], cw3.y, a3);
        a3 = fmaf(xzt[r + 2][cc4 + 3], cw3.z, a3);
        a3 = fmaf(xzt[r + 3][cc4 + 3], cw3.w, a3);
        float o0 = a0 / (1.f + __expf(-a0));
        float o1 = a1 / (1.f + __expf(-a1));
        float o2 = a2 / (1.f + __expf(-a2));
        float o3 = a3 / (1.f + __expf(-a3));
        *(float4*)&us[r][cc4] = make_float4(o0, o1, o2, o3);
        if (blockIdx.y == 0)
          *(float4*)(u_out + (size_t)(m0 + r) * 256 + d) =
              make_float4(o0, o1, o2, o3);
      }
    }
    __syncthreads();
#pragma unroll
    for (int kk = 0; kk < 64; kk += 4) {
      float4 a4 = *(const float4*)&us[lane][kk];
      float a_[4] = {a4.x, a4.y, a4.z, a4.w};
#pragma unroll
      for (int i = 0; i < 4; ++i)
#pragma unroll
        for (int j = 0; j < 5; ++j)
          acc[j] = fmaf(a_[i], Wb[j * 256 + k0 + kk + i], acc[j]);
    }
  }
  size_t base = (size_t)(m0 + lane) * 40 + jbase;
#pragma unroll
  for (int j = 0; j < 5; ++j) dbc[base + j] = acc[j];
}

// ---------------- K5: chunked parallel selective scan ----------------
// carryA eliminated: pass1 stores only dvs = sum(dv) per (chunk,d); scan_mid
// recomputes a = exp(dvs*Ac[n]) on the fly (saves ~33 MB carryA round-trip).
__device__ __forceinline__ float softplus_f(float a) {
  return (a > 20.f) ? a : log1pf(__expf(a));
}

__global__ __launch_bounds__(256) void scan_pass1(
    const float* __restrict__ u, const float* __restrict__ dbc,
    const float* __restrict__ A_log, const float* __restrict__ Wdt,
    const float* __restrict__ bdt, float* __restrict__ dvs_buf,
    float* __restrict__ carryH) {
  int bid = blockIdx.x;          // b*NC + c
  int b = bid >> 7;
  int c = bid & (NC - 1);
  int d = threadIdx.x;
  __shared__ float ls[CHUNK * 40];
  size_t l0 = (size_t)b * L_SEQ + (size_t)c * CHUNK;
  const float* rp = dbc + l0 * 40;
  for (int e = d; e < CHUNK * 40; e += 256) ls[e] = rp[e];
  float Ac[16];
  {
    const float4* ar = (const float4*)(A_log + d * 16);
#pragma unroll
    for (int q = 0; q < 4; ++q) {
      float4 v = ar[q];
      Ac[q * 4 + 0] = -__expf(v.x); Ac[q * 4 + 1] = -__expf(v.y);
      Ac[q * 4 + 2] = -__expf(v.z); Ac[q * 4 + 3] = -__expf(v.w);
    }
  }
  float wdt[8];
  {
    const float4* wr = (const float4*)(Wdt + d * 8);
    float4 v0 = wr[0], v1 = wr[1];
    wdt[0] = v0.x; wdt[1] = v0.y; wdt[2] = v0.z; wdt[3] = v0.w;
    wdt[4] = v1.x; wdt[5] = v1.y; wdt[6] = v1.z; wdt[7] = v1.w;
  }
  float bdt_v = bdt[d];
  const float* up = u + l0 * 256 + d;
  __syncthreads();
  float h[16];
#pragma unroll
  for (int n = 0; n < 16; ++n) h[n] = 0.f;
  float dvs = 0.f;
#pragma unroll 4
  for (int li = 0; li < CHUNK; ++li) {
    float uv = up[(size_t)li * 256];
    float acc = bdt_v;
#pragma unroll
    for (int j = 0; j < 8; ++j)
      acc = fmaf(ls[li * 40 + j], wdt[j], acc);
    float dv = softplus_f(acc);
    dvs += dv;
    float t = dv * uv;
#pragma unroll
    for (int n = 0; n < 16; ++n) {
      float dA = __expf(dv * Ac[n]);
      h[n] = fmaf(dA, h[n], t * ls[li * 40 + 8 + n]);
    }
  }
  dvs_buf[(size_t)bid * 256 + d] = dvs;
  float4* cH = (float4*)(carryH + ((size_t)bid * 256 + d) * 16);
#pragma unroll
  for (int q = 0; q < 4; ++q)
    cH[q] = make_float4(h[q * 4], h[q * 4 + 1], h[q * 4 + 2], h[q * 4 + 3]);
}

// h = exp(dvs*Ac)*h + h_local per chunk; (dvs,hl) prefetched one iter ahead.
__global__ __launch_bounds__(256) void scan_mid(
    const float* __restrict__ dvs_buf, const float* __restrict__ A_log,
    float* __restrict__ carryH) {
  int gid = blockIdx.x * 256 + threadIdx.x;  // 16384 chains = (b, d, n)
  int b = gid >> 12;
  int dn = gid & 4095;
  int d = dn >> 4;
  float Ac = -__expf(A_log[dn]);
  size_t ib = ((size_t)(b * NC) << 12) + dn;   // carryH index, step 4096
  size_t id = (size_t)(b * NC) * 256 + d;      // dvs index, step 256
  float h = 0.f;
  float dv = dvs_buf[id];
  float hl = carryH[ib];
  for (int c = 0; c < NC - 1; ++c) {
    float dv2 = dvs_buf[id + 256];
    float hl2 = carryH[ib + 4096];
    carryH[ib] = h;                 // h entering chunk c
    h = fmaf(__expf(dv * Ac), h, hl);
    dv = dv2; hl = hl2; ib += 4096; id += 256;
  }
  carryH[ib] = h;                   // h entering last chunk
}

__global__ __launch_bounds__(256) void scan_pass3(
    const float* __restrict__ u, const float* __restrict__ dbc,
    const float* __restrict__ xz, const float* __restrict__ A_log,
    const float* __restrict__ Wdt, const float* __restrict__ bdt,
    const float* __restrict__ Dp, const float* __restrict__ carryH,
    float* __restrict__ y) {
  int bid = blockIdx.x;
  int b = bid >> 7;
  int c = bid & (NC - 1);
  int d = threadIdx.x;
  __shared__ float ls[CHUNK * 40];
  size_t l0 = (size_t)b * L_SEQ + (size_t)c * CHUNK;
  const float* rp = dbc + l0 * 40;
  for (int e = d; e < CHUNK * 40; e += 256) ls[e] = rp[e];
  float Ac[16];
  {
    const float4* ar = (const float4*)(A_log + d * 16);
#pragma unroll
    for (int q = 0; q < 4; ++q) {
      float4 v = ar[q];
      Ac[q * 4 + 0] = -__expf(v.x); Ac[q * 4 + 1] = -__expf(v.y);
      Ac[q * 4 + 2] = -__expf(v.z); Ac[q * 4 + 3] = -__expf(v.w);
    }
  }
  float wdt[8];
  {
    const float4* wr = (const float4*)(Wdt + d * 8);
    float4 v0 = wr[0], v1 = wr[1];
    wdt[0] = v0.x; wdt[1] = v0.y; wdt[2] = v0.z; wdt[3] = v0.w;
    wdt[4] = v1.x; wdt[5] = v1.y; wdt[6] = v1.z; wdt[7] = v1.w;
  }
  float bdt_v = bdt[d];
  float Dv = Dp[d];
  float h[16];
  {
    const float4* cH = (const float4*)(carryH + ((size_t)bid * 256 + d) * 16);
#pragma unroll
    for (int q = 0; q < 4; ++q) {
      float4 v = cH[q];
      h[q * 4 + 0] = v.x; h[q * 4 + 1] = v.y;
      h[q * 4 + 2] = v.z; h[q * 4 + 3] = v.w;
    }
  }
  const float* up = u + l0 * 256 + d;
  const float* zp = xz + l0 * 512 + 256 + d;
  float* yp = y + l0 * 256 + d;
  __syncthreads();
#pragma unroll 4
  for (int li = 0; li < CHUNK; ++li) {
    float uv = up[(size_t)li * 256];
    float zv = zp[(size_t)li * 512];
    float acc = bdt_v;
#pragma unroll
    for (int j = 0; j < 8; ++j)
      acc = fmaf(ls[li * 40 + j], wdt[j], acc);
    float dv = softplus_f(acc);
    float t = dv * uv;
    float p = 0.f;
#pragma unroll
    for (int n = 0; n < 16; ++n) {
      float dA = __expf(dv * Ac[n]);
      h[n] = fmaf(dA, h[n], t * ls[li * 40 + 8 + n]);
      p = fmaf(h[n], ls[li * 40 + 24 + n], p);
    }
    float s = zv / (1.f + __expf(-zv));
    yp[(size_t)li * 256] = (p + uv * Dv) * s;
  }
}

// ---------------- K6: LayerNorm(ch) + silu + 1x1 conv -> out (B,64,H2,W2)
__global__ __launch_bounds__(256) void ln_out_kernel(
    const float* __restrict__ s2, const float* __restrict__ gamma,
    const float* __restrict__ beta, const float* __restrict__ Wo,
    const float* __restrict__ bo, float* __restrict__ out) {
  __shared__ float xt[64][129];
  __shared__ float mus[64], invs[64];
  int tid = threadIdx.x;
  int m0 = blockIdx.x * 64;
  // Phase A: coalesced tile load -> LDS
  for (int i = 0; i < 8; ++i) {
    int s = tid + i * 256;          // 2048 float4 slots
    int r = s >> 5, q = s & 31;
    float4 v = *(const float4*)(s2 + (size_t)(m0 + r) * 128 + q * 4);
    xt[r][q * 4 + 0] = v.x; xt[r][q * 4 + 1] = v.y;
    xt[r][q * 4 + 2] = v.z; xt[r][q * 4 + 3] = v.w;
  }
  __syncthreads();
  // Phase B: stats, 4 threads per row
  {
    int r = tid >> 2, kq = (tid & 3) * 32;
    float s = 0.f, q = 0.f;
#pragma unroll 8
    for (int kk = 0; kk < 32; ++kk) {
      float v = xt[r][kq + kk];
      s += v; q = fmaf(v, v, q);
    }
    s += __shfl_xor(s, 1, 64); s += __shfl_xor(s, 2, 64);
    q += __shfl_xor(q, 1, 64); q += __shfl_xor(q, 2, 64);
    if ((tid & 3) == 0) {
      float mu = s * (1.f / 128.f);
      float var = q * (1.f / 128.f) - mu * mu;
      mus[r] = mu;
      invs[r] = rsqrtf(var + 1e-5f);
    }
  }
  __syncthreads();
  // Phase T: LN + silu in-place
  for (int i = 0; i < 32; ++i) {
    int idx = tid + i * 256;        // 8192 elements
    int r = idx >> 7, k = idx & 127;
    float v = xt[r][k];
    float xn = (v - mus[r]) * invs[r] * gamma[k] + beta[k];
    xt[r][k] = xn / (1.f + __expf(-xn));
  }
  __syncthreads();
  // Phase C: GEMM, lane = row, wave-uniform channels
  int lane = tid & 63;
  int w = __builtin_amdgcn_readfirstlane(tid >> 6);
  int cbase = blockIdx.y * 32 + w * 8;
  const float* Wrow = Wo + cbase * 128;
  float acc[8];
#pragma unroll
  for (int j = 0; j < 8; ++j) acc[j] = 0.f;
#pragma unroll 4
  for (int k = 0; k < 128; ++k) {
    float v = xt[lane][k];
#pragma unroll
    for (int j = 0; j < 8; ++j)
      acc[j] = fmaf(v, Wrow[j * 128 + k], acc[j]);
  }
  int m = m0 + lane;
  int b = m >> 12, l = m & 4095;
#pragma unroll
  for (int j = 0; j < 8; ++j)
    out[((size_t)b * 64 + cbase + j) * 4096 + l] = acc[j] + bo[cbase + j];
}

extern "C" void kernel_launch(void* const* d_in, const int* in_sizes, int n_in,
                              void* d_out, int out_size, void* d_ws, size_t ws_size,
                              hipStream_t stream) {
  (void)in_sizes; (void)n_in; (void)out_size; (void)ws_size;
  const float* x         = (const float*)d_in[0];
  const float* skip      = (const float*)d_in[1];
  const float* up_w      = (const float*)d_in[2];
  const float* up_b      = (const float*)d_in[3];
  const float* in_proj_w = (const float*)d_in[4];
  const float* conv1d_w  = (const float*)d_in[5];
  const float* conv1d_b  = (const float*)d_in[6];
  const float* x_proj_w  = (const float*)d_in[7];
  const float* dt_proj_w = (const float*)d_in[8];
  const float* dt_proj_b = (const float*)d_in[9];
  const float* A_log     = (const float*)d_in[10];
  const float* Dp        = (const float*)d_in[11];
  const float* out_proj_w= (const float*)d_in[12];
  const float* ln_gamma  = (const float*)d_in[13];
  const float* ln_beta   = (const float*)d_in[14];
  const float* convout_w = (const float*)d_in[15];
  const float* convout_b = (const float*)d_in[16];
  float* out = (float*)d_out;
  float* ws  = (float*)d_ws;

  // workspace layout (floats)
  float* seq    = ws;                  // 2,097,152  (reused as s2 after out_proj)
  float* xz     = ws + 2097152;        // 8,388,608
  float* u      = ws + 10485760;       // 4,194,304
  float* dbc    = ws + 14680064;       //   655,360
  float* y      = ws + 15335424;       // 4,194,304
  float* dvs    = ws + 19529728;       //   131,072  (was carryA)
  float* carryH = ws + 21626880;       // 2,097,152

  upcat_kernel<<<256, 256, 0, stream>>>(x, skip, up_w, up_b, seq);
  gemm_bt128<<<dim3(16384 / 128, 512 / 64), 256, 0, stream>>>(
      seq, in_proj_w, xz, 16384, 512, 128);
  xproj_kernel<<<dim3(16384 / 64, 2), 256, 0, stream>>>(
      xz, conv1d_w, conv1d_b, x_proj_w, dbc, u);
  scan_pass1<<<4 * NC, 256, 0, stream>>>(u, dbc, A_log, dt_proj_w, dt_proj_b,
                                         dvs, carryH);
  scan_mid<<<64, 256, 0, stream>>>(dvs, A_log, carryH);
  scan_pass3<<<4 * NC, 256, 0, stream>>>(u, dbc, xz, A_log, dt_proj_w,
                                         dt_proj_b, Dp, carryH, y);
  gemm_bt<<<dim3(16384 / 64, 128 / 64), 256, 0, stream>>>(y, out_proj_w, seq,
                                                          16384, 128, 256);
  ln_out_kernel<<<dim3(256, 2), 256, 0, stream>>>(seq, ln_gamma, ln_beta,
                                                  convout_w, convout_b, out);
}

// Round 17
// 193.659 us; speedup vs baseline: 1.1611x; 1.0414x over previous
//
#include <hip/hip_runtime.h>

#define L_SEQ 4096
#define DM 128
#define DIN 256
#define NC 128       // scan chunks
#define CHUNK 32     // L_SEQ / NC

// ---------------- K1: ConvTranspose2d(2x2,s2) + bias + concat -> seq (B,L,128)
__global__ __launch_bounds__(256) void upcat_kernel(
    const float* __restrict__ x, const float* __restrict__ skip,
    const float* __restrict__ up_w, const float* __restrict__ up_b,
    float* __restrict__ seq) {
  int b = blockIdx.x >> 6, hh = blockIdx.x & 63;
  int h = hh >> 1, i = hh & 1;
  int tid = threadIdx.x;
  __shared__ float xs[128][32];      // x[b][c][h][:]
  __shared__ float wsh[2][128][64];  // [j][c][o] for this i
  for (int e = tid; e < 1024; e += 256) {
    int c = e >> 3, q = e & 7;
    *(float4*)&xs[c][q * 4] =
        *(const float4*)(x + (((size_t)b * 128 + c) * 32 + h) * 32 + q * 4);
  }
  for (int e = tid; e < 8192; e += 256) {
    int c = e >> 6, o = e & 63;
    float2 v = *(const float2*)(up_w + c * 256 + o * 4 + i * 2);
    wsh[0][c][o] = v.x;
    wsh[1][c][o] = v.y;
  }
  __syncthreads();
  int tx = tid & 15, ty = tid >> 4;  // o-quad, ww-quad
  float4 bv = *(const float4*)(up_b + tx * 4);
  float acc[4][4];                   // [a -> ww=ty*4+a][o]
#pragma unroll
  for (int a = 0; a < 4; ++a) {
    acc[a][0] = bv.x; acc[a][1] = bv.y; acc[a][2] = bv.z; acc[a][3] = bv.w;
  }
#pragma unroll 4
  for (int c = 0; c < 128; ++c) {
    float x0 = xs[c][ty * 2];        // ww = 4ty+0,1  (w = 2ty)
    float x1 = xs[c][ty * 2 + 1];    // ww = 4ty+2,3  (w = 2ty+1)
    float4 w0 = *(const float4*)&wsh[0][c][tx * 4];
    float4 w1 = *(const float4*)&wsh[1][c][tx * 4];
    acc[0][0] = fmaf(x0, w0.x, acc[0][0]); acc[0][1] = fmaf(x0, w0.y, acc[0][1]);
    acc[0][2] = fmaf(x0, w0.z, acc[0][2]); acc[0][3] = fmaf(x0, w0.w, acc[0][3]);
    acc[1][0] = fmaf(x0, w1.x, acc[1][0]); acc[1][1] = fmaf(x0, w1.y, acc[1][1]);
    acc[1][2] = fmaf(x0, w1.z, acc[1][2]); acc[1][3] = fmaf(x0, w1.w, acc[1][3]);
    acc[2][0] = fmaf(x1, w0.x, acc[2][0]); acc[2][1] = fmaf(x1, w0.y, acc[2][1]);
    acc[2][2] = fmaf(x1, w0.z, acc[2][2]); acc[2][3] = fmaf(x1, w0.w, acc[2][3]);
    acc[3][0] = fmaf(x1, w1.x, acc[3][0]); acc[3][1] = fmaf(x1, w1.y, acc[3][1]);
    acc[3][2] = fmaf(x1, w1.z, acc[3][2]); acc[3][3] = fmaf(x1, w1.w, acc[3][3]);
  }
  size_t mrow_base = (size_t)b * L_SEQ + (size_t)hh * 64;
#pragma unroll
  for (int a = 0; a < 4; ++a) {
    int ww = ty * 4 + a;
    *(float4*)(seq + (mrow_base + ww) * DM + tx * 4) =
        make_float4(acc[a][0], acc[a][1], acc[a][2], acc[a][3]);
  }
  // skip half: channels 64..127
  for (int e = tid; e < 4096; e += 256) {
    int c = e & 63, ww = e >> 6;
    seq[(mrow_base + ww) * DM + 64 + c] =
        skip[((size_t)b * 64 + c) * (size_t)L_SEQ + hh * 64 + ww];
  }
}

// ---------------- fp32 GEMM, 128x64 tile, 8x4 acc/thread (in_proj)
__global__ __launch_bounds__(256) void gemm_bt128(
    const float* __restrict__ A, const float* __restrict__ W,
    float* __restrict__ C, int M, int N, int K) {
  __shared__ float As[32][132];  // [k][m], pad 132
  __shared__ float Ws[32][68];   // [k][n], pad 68
  int m0 = blockIdx.x * 128, n0 = blockIdx.y * 64;
  int tid = threadIdx.x;
  int tx = tid & 15, ty = tid >> 4;
  float acc[8][4];
#pragma unroll
  for (int a = 0; a < 8; ++a)
#pragma unroll
    for (int bb = 0; bb < 4; ++bb) acc[a][bb] = 0.f;

  for (int k0 = 0; k0 < K; k0 += 32) {
    __syncthreads();
    for (int e = tid; e < 1024; e += 256) {
      int r = e >> 3, c4 = (e & 7) << 2;
      float4 va = *(const float4*)(A + (size_t)(m0 + r) * K + k0 + c4);
      As[c4 + 0][r] = va.x; As[c4 + 1][r] = va.y;
      As[c4 + 2][r] = va.z; As[c4 + 3][r] = va.w;
    }
    for (int e = tid; e < 512; e += 256) {
      int r = e >> 3, c4 = (e & 7) << 2;
      float4 vw = *(const float4*)(W + (size_t)(n0 + r) * K + k0 + c4);
      Ws[c4 + 0][r] = vw.x; Ws[c4 + 1][r] = vw.y;
      Ws[c4 + 2][r] = vw.z; Ws[c4 + 3][r] = vw.w;
    }
    __syncthreads();
#pragma unroll
    for (int kk = 0; kk < 32; ++kk) {
      float4 a0 = *(const float4*)(&As[kk][ty * 8]);
      float4 a1 = *(const float4*)(&As[kk][ty * 8 + 4]);
      float4 wv = *(const float4*)(&Ws[kk][tx * 4]);
      float a_[8] = {a0.x, a0.y, a0.z, a0.w, a1.x, a1.y, a1.z, a1.w};
      float w_[4] = {wv.x, wv.y, wv.z, wv.w};
#pragma unroll
      for (int a = 0; a < 8; ++a)
#pragma unroll
        for (int bb = 0; bb < 4; ++bb)
          acc[a][bb] = fmaf(a_[a], w_[bb], acc[a][bb]);
    }
  }
#pragma unroll
  for (int a = 0; a < 8; ++a)
#pragma unroll
    for (int bb = 0; bb < 4; ++bb)
      C[(size_t)(m0 + ty * 8 + a) * N + n0 + tx * 4 + bb] = acc[a][bb];
}

// ---------------- generic fp32 GEMM: 64x64 tile (out_proj)
__global__ __launch_bounds__(256) void gemm_bt(
    const float* __restrict__ A, const float* __restrict__ W,
    float* __restrict__ C, int M, int N, int K) {
  __shared__ float As[32][68];  // [k][m], pad 68
  __shared__ float Ws[32][68];  // [k][n]
  int m0 = blockIdx.x * 64, n0 = blockIdx.y * 64;
  int tid = threadIdx.x;
  int tx = tid & 15, ty = tid >> 4;
  float acc[4][4];
#pragma unroll
  for (int a = 0; a < 4; ++a)
#pragma unroll
    for (int bb = 0; bb < 4; ++bb) acc[a][bb] = 0.f;

  for (int k0 = 0; k0 < K; k0 += 32) {
    __syncthreads();
    for (int e = tid; e < 512; e += 256) {
      int r = e >> 3;
      int c4 = (e & 7) << 2;
      float4 va = *(const float4*)(A + (size_t)(m0 + r) * K + k0 + c4);
      As[c4 + 0][r] = va.x; As[c4 + 1][r] = va.y;
      As[c4 + 2][r] = va.z; As[c4 + 3][r] = va.w;
      float4 vw = *(const float4*)(W + (size_t)(n0 + r) * K + k0 + c4);
      Ws[c4 + 0][r] = vw.x; Ws[c4 + 1][r] = vw.y;
      Ws[c4 + 2][r] = vw.z; Ws[c4 + 3][r] = vw.w;
    }
    __syncthreads();
#pragma unroll
    for (int kk = 0; kk < 32; ++kk) {
      float4 av = *(const float4*)(&As[kk][ty * 4]);
      float4 wv = *(const float4*)(&Ws[kk][tx * 4]);
      float av_[4] = {av.x, av.y, av.z, av.w};
      float wv_[4] = {wv.x, wv.y, wv.z, wv.w};
#pragma unroll
      for (int a = 0; a < 4; ++a)
#pragma unroll
        for (int bb = 0; bb < 4; ++bb)
          acc[a][bb] = fmaf(av_[a], wv_[bb], acc[a][bb]);
    }
  }
#pragma unroll
  for (int a = 0; a < 4; ++a)
#pragma unroll
    for (int bb = 0; bb < 4; ++bb)
      C[(size_t)(m0 + ty * 4 + a) * N + n0 + tx * 4 + bb] = acc[a][bb];
}

// ---------------- K4: fused conv1d+silu+xproj: xz -> u (global), dbc
__global__ __launch_bounds__(256) void xproj_kernel(
    const float* __restrict__ xz, const float* __restrict__ cw,
    const float* __restrict__ cb, const float* __restrict__ W,
    float* __restrict__ dbc, float* __restrict__ u_out) {
  __shared__ float xzt[67][64];  // raw xz rows (m0-3+rr)
  __shared__ float us[64][68];   // silu(conv(xz)) = u tile, pad 68
  int m0 = blockIdx.x * 64;
  int tid = threadIdx.x;
  int lane = tid & 63;
  int w = __builtin_amdgcn_readfirstlane(tid >> 6);  // wave-uniform 0..3
  int jbase = blockIdx.y * 20 + w * 5;
  const float* Wb = W + jbase * 256;
  bool first = (m0 & (L_SEQ - 1)) == 0;  // block at sequence start
  int cc4 = (tid & 15) << 2;             // conv-phase column group
  int r0 = tid >> 4;                     // conv-phase row base
  float acc[5];
#pragma unroll
  for (int j = 0; j < 5; ++j) acc[j] = 0.f;
  for (int k0 = 0; k0 < 256; k0 += 64) {
    __syncthreads();
    // stage raw xz (u-half) rows m0-3 .. m0+63 for cols k0..k0+63
    for (int e = tid; e < 67 * 16; e += 256) {
      int rr = e >> 4, c4 = (e & 15) << 2;
      float4 v;
      if (first && rr < 3)
        v = make_float4(0.f, 0.f, 0.f, 0.f);
      else
        v = *(const float4*)(xz + (size_t)(m0 - 3 + rr) * 512 + k0 + c4);
      *(float4*)&xzt[rr][c4] = v;
    }
    __syncthreads();
    // conv + silu -> us (and u global, y==0 only)
    {
      int d = k0 + cc4;
      float4 cw0 = *(const float4*)(cw + (d + 0) * 4);
      float4 cw1 = *(const float4*)(cw + (d + 1) * 4);
      float4 cw2 = *(const float4*)(cw + (d + 2) * 4);
      float4 cw3 = *(const float4*)(cw + (d + 3) * 4);
      float4 cbv = *(const float4*)(cb + d);
#pragma unroll
      for (int s = 0; s < 4; ++s) {
        int r = r0 + s * 16;
        float a0 = cbv.x, a1 = cbv.y, a2 = cbv.z, a3 = cbv.w;
        a0 = fmaf(xzt[r + 0][cc4 + 0], cw0.x, a0);
        a0 = fmaf(xzt[r + 1][cc4 + 0], cw0.y, a0);
        a0 = fmaf(xzt[r + 2][cc4 + 0], cw0.z, a0);
        a0 = fmaf(xzt[r + 3][cc4 + 0], cw0.w, a0);
        a1 = fmaf(xzt[r + 0][cc4 + 1], cw1.x, a1);
        a1 = fmaf(xzt[r + 1][cc4 + 1], cw1.y, a1);
        a1 = fmaf(xzt[r + 2][cc4 + 1], cw1.z, a1);
        a1 = fmaf(xzt[r + 3][cc4 + 1], cw1.w, a1);
        a2 = fmaf(xzt[r + 0][cc4 + 2], cw2.x, a2);
        a2 = fmaf(xzt[r + 1][cc4 + 2], cw2.y, a2);
        a2 = fmaf(xzt[r + 2][cc4 + 2], cw2.z, a2);
        a2 = fmaf(xzt[r + 3][cc4 + 2], cw2.w, a2);
        a3 = fmaf(xzt[r + 0][cc4 + 3], cw3.x, a3);
        a3 = fmaf(xzt[r + 1][cc4 + 3], cw3.y, a3);
        a3 = fmaf(xzt[r + 2][cc4 + 3], cw3.z, a3);
        a3 = fmaf(xzt[r + 3][cc4 + 3], cw3.w, a3);
        float o0 = a0 / (1.f + __expf(-a0));
        float o1 = a1 / (1.f + __expf(-a1));
        float o2 = a2 / (1.f + __expf(-a2));
        float o3 = a3 / (1.f + __expf(-a3));
        *(float4*)&us[r][cc4] = make_float4(o0, o1, o2, o3);
        if (blockIdx.y == 0)
          *(float4*)(u_out + (size_t)(m0 + r) * 256 + d) =
              make_float4(o0, o1, o2, o3);
      }
    }
    __syncthreads();
    // GEMM off the u tile (wave-uniform W reads -> scalar loads)
#pragma unroll
    for (int kk = 0; kk < 64; kk += 4) {
      float4 a4 = *(const float4*)&us[lane][kk];
      float a_[4] = {a4.x, a4.y, a4.z, a4.w};
#pragma unroll
      for (int i = 0; i < 4; ++i)
#pragma unroll
        for (int j = 0; j < 5; ++j)
          acc[j] = fmaf(a_[i], Wb[j * 256 + k0 + kk + i], acc[j]);
    }
  }
  size_t base = (size_t)(m0 + lane) * 40 + jbase;
#pragma unroll
  for (int j = 0; j < 5; ++j) dbc[base + j] = acc[j];
}

// ---------------- K5: chunked parallel selective scan ----------------
__device__ __forceinline__ float softplus_f(float a) {
  return (a > 20.f) ? a : log1pf(__expf(a));
}

__global__ __launch_bounds__(256) void scan_pass1(
    const float* __restrict__ u, const float* __restrict__ dbc,
    const float* __restrict__ A_log, const float* __restrict__ Wdt,
    const float* __restrict__ bdt, float* __restrict__ carryA,
    float* __restrict__ carryH) {
  int bid = blockIdx.x;          // b*NC + c
  int b = bid >> 7;
  int c = bid & (NC - 1);
  int d = threadIdx.x;
  __shared__ float ls[CHUNK * 40];
  size_t l0 = (size_t)b * L_SEQ + (size_t)c * CHUNK;
  const float* rp = dbc + l0 * 40;
  for (int e = d; e < CHUNK * 40; e += 256) ls[e] = rp[e];
  float Ac[16];
  {
    const float4* ar = (const float4*)(A_log + d * 16);
#pragma unroll
    for (int q = 0; q < 4; ++q) {
      float4 v = ar[q];
      Ac[q * 4 + 0] = -__expf(v.x); Ac[q * 4 + 1] = -__expf(v.y);
      Ac[q * 4 + 2] = -__expf(v.z); Ac[q * 4 + 3] = -__expf(v.w);
    }
  }
  float wdt[8];
  {
    const float4* wr = (const float4*)(Wdt + d * 8);
    float4 v0 = wr[0], v1 = wr[1];
    wdt[0] = v0.x; wdt[1] = v0.y; wdt[2] = v0.z; wdt[3] = v0.w;
    wdt[4] = v1.x; wdt[5] = v1.y; wdt[6] = v1.z; wdt[7] = v1.w;
  }
  float bdt_v = bdt[d];
  const float* up = u + l0 * 256 + d;
  __syncthreads();
  float h[16];
#pragma unroll
  for (int n = 0; n < 16; ++n) h[n] = 0.f;
  float dvs = 0.f;
#pragma unroll 4
  for (int li = 0; li < CHUNK; ++li) {
    float uv = up[(size_t)li * 256];
    float acc = bdt_v;
#pragma unroll
    for (int j = 0; j < 8; ++j)
      acc = fmaf(ls[li * 40 + j], wdt[j], acc);
    float dv = softplus_f(acc);
    dvs += dv;
    float t = dv * uv;
#pragma unroll
    for (int n = 0; n < 16; ++n) {
      float dA = __expf(dv * Ac[n]);
      h[n] = fmaf(dA, h[n], t * ls[li * 40 + 8 + n]);
    }
  }
  float4* cA = (float4*)(carryA + ((size_t)bid * 256 + d) * 16);
  float4* cH = (float4*)(carryH + ((size_t)bid * 256 + d) * 16);
#pragma unroll
  for (int q = 0; q < 4; ++q) {
    // prod of dA over chunk == exp(sum(dv) * Ac)
    cA[q] = make_float4(__expf(dvs * Ac[q * 4]), __expf(dvs * Ac[q * 4 + 1]),
                        __expf(dvs * Ac[q * 4 + 2]), __expf(dvs * Ac[q * 4 + 3]));
    cH[q] = make_float4(h[q * 4], h[q * 4 + 1], h[q * 4 + 2], h[q * 4 + 3]);
  }
}

__global__ __launch_bounds__(256) void scan_mid(
    const float* __restrict__ carryA, float* __restrict__ carryH) {
  int gid = blockIdx.x * 256 + threadIdx.x;  // 16384 chains
  int b = gid >> 12;
  int dn = gid & 4095;
  float h = 0.f;
  for (int c = 0; c < NC; ++c) {
    size_t i = ((size_t)(b * NC + c) << 12) + dn;
    float a = carryA[i];
    float hl = carryH[i];
    carryH[i] = h;                 // h entering chunk c
    h = fmaf(a, h, hl);
  }
}

__global__ __launch_bounds__(256) void scan_pass3(
    const float* __restrict__ u, const float* __restrict__ dbc,
    const float* __restrict__ xz, const float* __restrict__ A_log,
    const float* __restrict__ Wdt, const float* __restrict__ bdt,
    const float* __restrict__ Dp, const float* __restrict__ carryH,
    float* __restrict__ y) {
  int bid = blockIdx.x;
  int b = bid >> 7;
  int c = bid & (NC - 1);
  int d = threadIdx.x;
  __shared__ float ls[CHUNK * 40];
  size_t l0 = (size_t)b * L_SEQ + (size_t)c * CHUNK;
  const float* rp = dbc + l0 * 40;
  for (int e = d; e < CHUNK * 40; e += 256) ls[e] = rp[e];
  float Ac[16];
  {
    const float4* ar = (const float4*)(A_log + d * 16);
#pragma unroll
    for (int q = 0; q < 4; ++q) {
      float4 v = ar[q];
      Ac[q * 4 + 0] = -__expf(v.x); Ac[q * 4 + 1] = -__expf(v.y);
      Ac[q * 4 + 2] = -__expf(v.z); Ac[q * 4 + 3] = -__expf(v.w);
    }
  }
  float wdt[8];
  {
    const float4* wr = (const float4*)(Wdt + d * 8);
    float4 v0 = wr[0], v1 = wr[1];
    wdt[0] = v0.x; wdt[1] = v0.y; wdt[2] = v0.z; wdt[3] = v0.w;
    wdt[4] = v1.x; wdt[5] = v1.y; wdt[6] = v1.z; wdt[7] = v1.w;
  }
  float bdt_v = bdt[d];
  float Dv = Dp[d];
  float h[16];
  {
    const float4* cH = (const float4*)(carryH + ((size_t)bid * 256 + d) * 16);
#pragma unroll
    for (int q = 0; q < 4; ++q) {
      float4 v = cH[q];
      h[q * 4 + 0] = v.x; h[q * 4 + 1] = v.y;
      h[q * 4 + 2] = v.z; h[q * 4 + 3] = v.w;
    }
  }
  const float* up = u + l0 * 256 + d;
  const float* zp = xz + l0 * 512 + 256 + d;
  float* yp = y + l0 * 256 + d;
  __syncthreads();
#pragma unroll 4
  for (int li = 0; li < CHUNK; ++li) {
    float uv = up[(size_t)li * 256];
    float zv = zp[(size_t)li * 512];
    float acc = bdt_v;
#pragma unroll
    for (int j = 0; j < 8; ++j)
      acc = fmaf(ls[li * 40 + j], wdt[j], acc);
    float dv = softplus_f(acc);
    float t = dv * uv;
    float p = 0.f;
#pragma unroll
    for (int n = 0; n < 16; ++n) {
      float dA = __expf(dv * Ac[n]);
      h[n] = fmaf(dA, h[n], t * ls[li * 40 + 8 + n]);
      p = fmaf(h[n], ls[li * 40 + 24 + n], p);
    }
    float s = zv / (1.f + __expf(-zv));
    yp[(size_t)li * 256] = (p + uv * Dv) * s;
  }
}

// ---------------- K6: LayerNorm(ch) + silu + 1x1 conv -> out (B,64,H2,W2)
__global__ __launch_bounds__(256) void ln_out_kernel(
    const float* __restrict__ s2, const float* __restrict__ gamma,
    const float* __restrict__ beta, const float* __restrict__ Wo,
    const float* __restrict__ bo, float* __restrict__ out) {
  __shared__ float xt[64][129];
  __shared__ float mus[64], invs[64];
  int tid = threadIdx.x;
  int m0 = blockIdx.x * 64;
  // Phase A: coalesced tile load -> LDS
  for (int i = 0; i < 8; ++i) {
    int s = tid + i * 256;          // 2048 float4 slots
    int r = s >> 5, q = s & 31;
    float4 v = *(const float4*)(s2 + (size_t)(m0 + r) * 128 + q * 4);
    xt[r][q * 4 + 0] = v.x; xt[r][q * 4 + 1] = v.y;
    xt[r][q * 4 + 2] = v.z; xt[r][q * 4 + 3] = v.w;
  }
  __syncthreads();
  // Phase B: stats, 4 threads per row
  {
    int r = tid >> 2, kq = (tid & 3) * 32;
    float s = 0.f, q = 0.f;
#pragma unroll 8
    for (int kk = 0; kk < 32; ++kk) {
      float v = xt[r][kq + kk];
      s += v; q = fmaf(v, v, q);
    }
    s += __shfl_xor(s, 1, 64); s += __shfl_xor(s, 2, 64);
    q += __shfl_xor(q, 1, 64); q += __shfl_xor(q, 2, 64);
    if ((tid & 3) == 0) {
      float mu = s * (1.f / 128.f);
      float var = q * (1.f / 128.f) - mu * mu;
      mus[r] = mu;
      invs[r] = rsqrtf(var + 1e-5f);
    }
  }
  __syncthreads();
  // Phase T: LN + silu in-place
  for (int i = 0; i < 32; ++i) {
    int idx = tid + i * 256;        // 8192 elements
    int r = idx >> 7, k = idx & 127;
    float v = xt[r][k];
    float xn = (v - mus[r]) * invs[r] * gamma[k] + beta[k];
    xt[r][k] = xn / (1.f + __expf(-xn));
  }
  __syncthreads();
  // Phase C: GEMM, lane = row, wave-uniform channels
  int lane = tid & 63;
  int w = __builtin_amdgcn_readfirstlane(tid >> 6);
  int cbase = blockIdx.y * 32 + w * 8;
  const float* Wrow = Wo + cbase * 128;
  float acc[8];
#pragma unroll
  for (int j = 0; j < 8; ++j) acc[j] = 0.f;
#pragma unroll 4
  for (int k = 0; k < 128; ++k) {
    float v = xt[lane][k];
#pragma unroll
    for (int j = 0; j < 8; ++j)
      acc[j] = fmaf(v, Wrow[j * 128 + k], acc[j]);
  }
  int m = m0 + lane;
  int b = m >> 12, l = m & 4095;
#pragma unroll
  for (int j = 0; j < 8; ++j)
    out[((size_t)b * 64 + cbase + j) * 4096 + l] = acc[j] + bo[cbase + j];
}

extern "C" void kernel_launch(void* const* d_in, const int* in_sizes, int n_in,
                              void* d_out, int out_size, void* d_ws, size_t ws_size,
                              hipStream_t stream) {
  (void)in_sizes; (void)n_in; (void)out_size; (void)ws_size;
  const float* x         = (const float*)d_in[0];
  const float* skip      = (const float*)d_in[1];
  const float* up_w      = (const float*)d_in[2];
  const float* up_b      = (const float*)d_in[3];
  const float* in_proj_w = (const float*)d_in[4];
  const float* conv1d_w  = (const float*)d_in[5];
  const float* conv1d_b  = (const float*)d_in[6];
  const float* x_proj_w  = (const float*)d_in[7];
  const float* dt_proj_w = (const float*)d_in[8];
  const float* dt_proj_b = (const float*)d_in[9];
  const float* A_log     = (const float*)d_in[10];
  const float* Dp        = (const float*)d_in[11];
  const float* out_proj_w= (const float*)d_in[12];
  const float* ln_gamma  = (const float*)d_in[13];
  const float* ln_beta   = (const float*)d_in[14];
  const float* convout_w = (const float*)d_in[15];
  const float* convout_b = (const float*)d_in[16];
  float* out = (float*)d_out;
  float* ws  = (float*)d_ws;

  // workspace layout (floats)
  float* seq    = ws;                  // 2,097,152
  float* xz     = ws + 2097152;        // 8,388,608
  float* u      = ws + 10485760;       // 4,194,304
  float* dbc    = ws + 14680064;       //   655,360
  float* y      = ws + 15335424;       // 4,194,304
  float* carryA = ws + 19529728;       // 2,097,152  (= 4*NC*256*16)
  float* carryH = ws + 21626880;       // 2,097,152

  upcat_kernel<<<256, 256, 0, stream>>>(x, skip, up_w, up_b, seq);
  gemm_bt128<<<dim3(16384 / 128, 512 / 64), 256, 0, stream>>>(
      seq, in_proj_w, xz, 16384, 512, 128);
  xproj_kernel<<<dim3(16384 / 64, 2), 256, 0, stream>>>(
      xz, conv1d_w, conv1d_b, x_proj_w, dbc, u);
  scan_pass1<<<4 * NC, 256, 0, stream>>>(u, dbc, A_log, dt_proj_w, dt_proj_b,
                                         carryA, carryH);
  scan_mid<<<64, 256, 0, stream>>>(carryA, carryH);
  scan_pass3<<<4 * NC, 256, 0, stream>>>(u, dbc, xz, A_log, dt_proj_w,
                                         dt_proj_b, Dp, carryH, y);
  gemm_bt<<<dim3(16384 / 64, 128 / 64), 256, 0, stream>>>(y, out_proj_w, seq,
                                                          16384, 128, 256);
  ln_out_kernel<<<dim3(256, 2), 256, 0, stream>>>(seq, ln_gamma, ln_beta,
                                                  convout_w, convout_b, out);
}